// Round 16
// baseline (2666.581 us; speedup 1.0000x reference)
//
#include <hip/hip_runtime.h>

// ---------------- model constants ----------------
#define NLAYER 4
#define DMODEL 2048
#define NHEAD  16
#define HEADD  128
#define FFDIM  8192
#define RLORA  16
#define SEQLEN 1024
#define NBATCH 2
#define NTOK   (NBATCH*SEQLEN)   // 2048
#define QKVS   6144              // fused qkv row stride

typedef __bf16 bf16x8 __attribute__((ext_vector_type(8)));
typedef float  f32x4  __attribute__((ext_vector_type(4)));
typedef unsigned short us8 __attribute__((ext_vector_type(8)));

__device__ __forceinline__ unsigned short f2b(float f) {
  unsigned int u = __builtin_bit_cast(unsigned int, f);
  u += 0x7FFFu + ((u >> 16) & 1u);          // round-to-nearest-even
  return (unsigned short)(u >> 16);
}
__device__ __forceinline__ float b2f(unsigned short s) {
  unsigned int u = ((unsigned int)s) << 16;
  return __builtin_bit_cast(float, u);
}
// V-LDS swizzle for attention
__device__ __forceinline__ int vswz(int d) {
  return (((d >> 2) & 7) ^ ((d & 3) << 1)) << 4;
}
typedef __attribute__((address_space(1))) const void* gas_t;
typedef __attribute__((address_space(3))) void* las_t;
__device__ __forceinline__ void gload16(const void* g, void* l) {
  __builtin_amdgcn_global_load_lds((gas_t)g, (las_t)l, 16, 0, 0);
}

// ---------------- embedding gather ----------------
__global__ void k_embed(const int* __restrict__ ids, const float* __restrict__ emb,
                        float* __restrict__ x) {
  int row = blockIdx.x;
  int id = ids[row];
  const float4* src = (const float4*)(emb + (size_t)id * DMODEL);
  float4* dst = (float4*)(x + (size_t)row * DMODEL);
  for (int i = threadIdx.x; i < DMODEL / 4; i += 256) dst[i] = src[i];
}

// ---------------- weight fp32 -> bf16 (branch-free) ----------------
__global__ void k_cvt16(const float* __restrict__ s, unsigned short* __restrict__ d, int n8) {
  int stride = gridDim.x * 256;
  for (int i = blockIdx.x * 256 + threadIdx.x; i < n8; i += stride) {
    size_t si = (size_t)i * 2;
    float4 a = ((const float4*)s)[si];
    float4 b = ((const float4*)s)[si + 1];
    us8 o;
    o[0]=f2b(a.x); o[1]=f2b(a.y); o[2]=f2b(a.z); o[3]=f2b(a.w);
    o[4]=f2b(b.x); o[5]=f2b(b.y); o[6]=f2b(b.z); o[7]=f2b(b.w);
    ((us8*)d)[i] = o;
  }
}

// merged Q/K/V conversion: dst layout per layer = [Wq | Wk | Wv]
__global__ void k_cvtqkv(const float* __restrict__ Wq, const float* __restrict__ Wk,
                         const float* __restrict__ Wv, unsigned short* __restrict__ d) {
  const size_t DD8 = (size_t)DMODEL * DMODEL / 8;      // 2^19
  const int n8 = (int)(NLAYER * 3 * DD8);
  int stride = gridDim.x * 256;
  for (int i = blockIdx.x * 256 + threadIdx.x; i < n8; i += stride) {
    int blk = i >> 19;
    int lay = blk / 3;
    int ten = blk - lay * 3;
    int off = i & ((1 << 19) - 1);
    const float* s = (ten == 0 ? Wq : ten == 1 ? Wk : Wv) + (size_t)lay * DMODEL * DMODEL;
    float4 a = ((const float4*)s)[(size_t)off * 2];
    float4 b = ((const float4*)s)[(size_t)off * 2 + 1];
    us8 o;
    o[0]=f2b(a.x); o[1]=f2b(a.y); o[2]=f2b(a.z); o[3]=f2b(a.w);
    o[4]=f2b(b.x); o[5]=f2b(b.y); o[6]=f2b(b.z); o[7]=f2b(b.w);
    ((us8*)(d))[(size_t)i] = o;
  }
}

// ---------------- RMSNorm -> bf16 ----------------
__global__ void k_rmsnorm(const float* __restrict__ x, const float* __restrict__ w,
                          unsigned short* __restrict__ h) {
  int row = blockIdx.x, t = threadIdx.x;
  const float* xr = x + (size_t)row * DMODEL;
  float4 a = ((const float4*)xr)[t];
  float4 b = ((const float4*)xr)[t + 256];
  float ss = a.x*a.x + a.y*a.y + a.z*a.z + a.w*a.w
           + b.x*b.x + b.y*b.y + b.z*b.z + b.w*b.w;
  for (int m = 32; m; m >>= 1) ss += __shfl_xor(ss, m);
  __shared__ float red[4];
  if ((t & 63) == 0) red[t >> 6] = ss;
  __syncthreads();
  ss = red[0] + red[1] + red[2] + red[3];
  float rs = rsqrtf(ss * (1.0f / DMODEL) + 1e-5f);
  float4 wa = ((const float4*)w)[t];
  float4 wb = ((const float4*)w)[t + 256];
  ushort4 oa, ob;
  oa.x = f2b(a.x * wa.x * rs); oa.y = f2b(a.y * wa.y * rs);
  oa.z = f2b(a.z * wa.z * rs); oa.w = f2b(a.w * wa.w * rs);
  ob.x = f2b(b.x * wb.x * rs); ob.y = f2b(b.y * wb.y * rs);
  ob.z = f2b(b.z * wb.z * rs); ob.w = f2b(b.w * wb.w * rs);
  ushort4* hr = (ushort4*)(h + (size_t)row * DMODEL);
  hr[t] = oa;
  hr[t + 256] = ob;
}

// ============ 256x256 tile GEMM, BK=64, 8 waves, 8-phase interleave ============
// m201-style: 4 phases per K-tile, each {8 ds_read || 2 gload_lds -> barrier ->
// lgkmcnt(0) -> setprio(1) 16 MFMA setprio(0) -> barrier}; depth-1 prefetch,
// vmcnt(0)+barrier once per K-tile (drains exactly the next tile's 8 loads).
// MODE 2: Cb = bf16(acc); MODE 3: Cb = bf16(silu(Gaux)*acc).
template<int MODE>
__global__ __launch_bounds__(512, 2)
void k_gemm8(const unsigned short* __restrict__ A, const unsigned short* __restrict__ B,
             unsigned short* __restrict__ Cb, const unsigned short* __restrict__ Gaux,
             int N, int K, int ldc) {
  __shared__ unsigned short LA[2][16384];   // [256][64] per buffer, 64KB
  __shared__ unsigned short LB[2][16384];   // 64KB
  const int t = threadIdx.x, l = t & 63, w = t >> 6;   // 8 waves
  const int wm = w >> 2, wn = w & 3;                    // 2M x 4N; wave out 128x64
  const int nbx = gridDim.x;                            // n tiles (32)
  const int nmt = gridDim.y;                            // m tiles (8)
  const int nwg = nbx * nmt;                            // 256
  const int bid = blockIdx.y * nbx + blockIdx.x;
  const int sid = (bid & 7) * (nwg >> 3) + (bid >> 3);
  const int m0 = (sid % nmt) << 8;                      // m fast
  const int n0 = (sid / nmt) << 8;                      // n sliced per XCD
  // staging: thread -> (row t>>3 in 0..63, slot t&7); rounds +64, halves +128
  const int srow = t >> 3;
  const int gcol = 8 * ((t & 7) ^ ((srow >> 1) & 7));
  const unsigned short* Ag = A + (size_t)(m0 + srow) * K + gcol;
  const unsigned short* Bg = B + (size_t)(n0 + srow) * K + gcol;
  const size_t r64K = (size_t)64 * K;
  const size_t r128K = (size_t)128 * K;
  const int cl = l & 15, lh = l >> 4;
  const int fR = (cl >> 1) & 7;
  f32x4 acc[8][4];
  #pragma unroll
  for (int mi = 0; mi < 8; mi++)
    #pragma unroll
    for (int ni = 0; ni < 4; ni++) { f32x4 z = {0.f,0.f,0.f,0.f}; acc[mi][ni] = z; }

#define STG_A(d, kt, hh_) do {                                               \
    const unsigned short* p_ = Ag + (size_t)(kt) * 64 + (size_t)(hh_) * r128K; \
    unsigned short* l_ = &LA[d][(hh_) * 8192 + (w << 9)];                    \
    gload16(p_,        l_);                                                  \
    gload16(p_ + r64K, l_ + 4096);                                           \
  } while (0)
#define STG_B(d, kt, hh_) do {                                               \
    const unsigned short* p_ = Bg + (size_t)(kt) * 64 + (size_t)(hh_) * r128K; \
    unsigned short* l_ = &LB[d][(hh_) * 8192 + (w << 9)];                    \
    gload16(p_,        l_);                                                  \
    gload16(p_ + r64K, l_ + 4096);                                           \
  } while (0)

  const int NT = K >> 6;
  // prologue: stage tile 0 fully into dbuf 0
  STG_A(0, 0, 0); STG_A(0, 0, 1); STG_B(0, 0, 0); STG_B(0, 0, 1);
  asm volatile("s_waitcnt vmcnt(0)" ::: "memory");
  __builtin_amdgcn_sched_barrier(0);
  __builtin_amdgcn_s_barrier();
  __builtin_amdgcn_sched_barrier(0);

  for (int t0 = 0; t0 < NT; ++t0) {
    const int cur = t0 & 1, nxt = cur ^ 1;
    const char* Ab = (const char*)&LA[cur][0];
    const char* Bb = (const char*)&LB[cur][0];
    const bool more = (t0 + 1 < NT);
    #pragma unroll
    for (int q = 0; q < 4; ++q) {
      const int mh = q & 1, kk = q >> 1;
      const int so = ((kk * 4 + lh) ^ fR) << 4;
      bf16x8 af[4], bf[4];
      #pragma unroll
      for (int mi = 0; mi < 4; mi++)
        af[mi] = *(const bf16x8*)(Ab + (wm*128 + mh*64 + mi*16 + cl) * 128 + so);
      #pragma unroll
      for (int ni = 0; ni < 4; ni++)
        bf[ni] = *(const bf16x8*)(Bb + (wn*64 + ni*16 + cl) * 128 + so);
      if (more) {
        if      (q == 0) STG_A(nxt, t0 + 1, 0);
        else if (q == 1) STG_A(nxt, t0 + 1, 1);
        else if (q == 2) STG_B(nxt, t0 + 1, 0);
        else             STG_B(nxt, t0 + 1, 1);
      }
      __builtin_amdgcn_sched_barrier(0);
      __builtin_amdgcn_s_barrier();
      asm volatile("s_waitcnt lgkmcnt(0)" ::: "memory");
      __builtin_amdgcn_sched_barrier(0);
      __builtin_amdgcn_s_setprio(1);
      #pragma unroll
      for (int mi = 0; mi < 4; mi++)
        #pragma unroll
        for (int ni = 0; ni < 4; ni++)
          acc[mh*4 + mi][ni] =
            __builtin_amdgcn_mfma_f32_16x16x32_bf16(af[mi], bf[ni], acc[mh*4 + mi][ni], 0, 0, 0);
      __builtin_amdgcn_s_setprio(0);
      __builtin_amdgcn_sched_barrier(0);
      __builtin_amdgcn_s_barrier();
      __builtin_amdgcn_sched_barrier(0);
    }
    if (more) {
      asm volatile("s_waitcnt vmcnt(0)" ::: "memory");   // next tile's 8 loads (depth-1)
      __builtin_amdgcn_sched_barrier(0);
      __builtin_amdgcn_s_barrier();
      __builtin_amdgcn_sched_barrier(0);
    }
  }
#undef STG_A
#undef STG_B
  const int rbase = lh << 2;
  #pragma unroll
  for (int mi = 0; mi < 8; mi++) {
    #pragma unroll
    for (int ni = 0; ni < 4; ni++) {
      #pragma unroll
      for (int rr = 0; rr < 4; rr++) {
        int row = m0 + wm * 128 + mi * 16 + rbase + rr;
        int col = n0 + wn * 64 + ni * 16 + cl;
        size_t idx = (size_t)row * ldc + col;
        float val = acc[mi][ni][rr];
        if constexpr (MODE == 3) {
          float gv = b2f(Gaux[idx]);
          val *= gv / (1.0f + __expf(-gv));
        }
        Cb[idx] = f2b(val);
      }
    }
  }
}

// ============ 64x128 tile GEMM, BK=128, 4 waves, single-buffer 48KB ============
// 2D XCD chunking (4m x 2n) for square-ish GEMMs (Wo, Wd).
template<int MODE>
__global__ __launch_bounds__(256, 4)
void k_gemm6(const unsigned short* __restrict__ A, const unsigned short* __restrict__ B,
             float* __restrict__ Cf, unsigned short* __restrict__ Cb,
             const float* __restrict__ Res, const unsigned short* __restrict__ Gaux,
             int N, int K, int ldc) {
  __shared__ unsigned short As[8192];    // 64 x 128  (16KB)
  __shared__ unsigned short Bs[16384];   // 128 x 128 (32KB)
  const int t = threadIdx.x, l = t & 63, w = t >> 6;
  const int nbx = gridDim.x;
  const int nmt = gridDim.y;
  const int bid = blockIdx.y * nbx + blockIdx.x;
  const int xcd = bid & 7;
  const int local = bid >> 3;
  const int cm = nmt >> 2;
  const int cn = nbx >> 1;
  const int m0 = ((xcd & 3) * cm + (local % cm)) << 6;
  const int n0 = ((xcd >> 2) * cn + (local / cm)) << 7;
  const int srow = (w << 2) + (l >> 4);                // 0..15
  const int gcol = 8 * ((l & 15) ^ ((srow >> 1) & 7));
  const unsigned short* Ag = A + (size_t)(m0 + srow) * K + gcol;
  const unsigned short* Bg = B + (size_t)(n0 + srow) * K + gcol;
  const size_t r16K = (size_t)16 * K;
  unsigned short* AsW = As + (w << 9);
  unsigned short* BsW = Bs + (w << 9);
  const int cl = l & 15, lh = l >> 4;
  const int fR = (cl >> 1) & 7;
  f32x4 acc[4][2];
  #pragma unroll
  for (int mi = 0; mi < 4; mi++)
    #pragma unroll
    for (int ni = 0; ni < 2; ni++) { f32x4 z = {0.f,0.f,0.f,0.f}; acc[mi][ni] = z; }

  for (int kt = 0; kt < K; kt += 128) {
    gload16(Ag + kt,          AsW);
    gload16(Ag + kt +   r16K, AsW + 2048);
    gload16(Ag + kt + 2*r16K, AsW + 4096);
    gload16(Ag + kt + 3*r16K, AsW + 6144);
    gload16(Bg + kt,          BsW);
    gload16(Bg + kt +   r16K, BsW + 2048);
    gload16(Bg + kt + 2*r16K, BsW + 4096);
    gload16(Bg + kt + 3*r16K, BsW + 6144);
    gload16(Bg + kt + 4*r16K, BsW + 8192);
    gload16(Bg + kt + 5*r16K, BsW + 10240);
    gload16(Bg + kt + 6*r16K, BsW + 12288);
    gload16(Bg + kt + 7*r16K, BsW + 14336);
    __syncthreads();
    #pragma unroll
    for (int kk = 0; kk < 4; kk++) {
      const int so = ((kk * 4 + lh) ^ fR) << 4;
      bf16x8 af[4], bf[2];
      #pragma unroll
      for (int mi = 0; mi < 4; mi++)
        af[mi] = *(const bf16x8*)((const char*)As + (mi*16 + cl) * 256 + so);
      #pragma unroll
      for (int ni = 0; ni < 2; ni++)
        bf[ni] = *(const bf16x8*)((const char*)Bs + (w*32 + ni*16 + cl) * 256 + so);
      #pragma unroll
      for (int mi = 0; mi < 4; mi++)
        #pragma unroll
        for (int ni = 0; ni < 2; ni++)
          acc[mi][ni] = __builtin_amdgcn_mfma_f32_16x16x32_bf16(af[mi], bf[ni], acc[mi][ni], 0, 0, 0);
    }
    __syncthreads();
  }
  const int rbase = lh << 2;
  #pragma unroll
  for (int mi = 0; mi < 4; mi++) {
    #pragma unroll
    for (int ni = 0; ni < 2; ni++) {
      #pragma unroll
      for (int rr = 0; rr < 4; rr++) {
        int row = m0 + mi * 16 + rbase + rr;
        int col = n0 + w * 32 + ni * 16 + cl;
        size_t idx = (size_t)row * ldc + col;
        float val = acc[mi][ni][rr];
        if constexpr (MODE == 0) Cf[idx] = val;
        if constexpr (MODE == 1) Cf[idx] = val + Res[idx];
        if constexpr (MODE == 2) Cb[idx] = f2b(val);
        if constexpr (MODE == 3) {
          float gv = b2f(Gaux[idx]);
          val *= gv / (1.0f + __expf(-gv));
          Cb[idx] = f2b(val);
        }
      }
    }
  }
}

// ============ QKV GEMM + fused LoRA + fused RoPE -> dense bf16 qb/kb/vb =========
__global__ __launch_bounds__(256, 4)
void k_gemm7(const unsigned short* __restrict__ A, const unsigned short* __restrict__ B,
             unsigned short* __restrict__ qb, unsigned short* __restrict__ kb,
             unsigned short* __restrict__ vb,
             const float* __restrict__ ct, const float* __restrict__ st,
             int K,
             const float* __restrict__ ltq, const float* __restrict__ ltv,
             const float* __restrict__ lbq, const float* __restrict__ lbv) {
  __shared__ unsigned short As[4096];    // 64 x 64  (8KB)
  __shared__ unsigned short Bs[8192];    // 128 x 64 (16KB)
  const int t = threadIdx.x, l = t & 63, w = t >> 6;
  const int nbx = gridDim.x;                           // 48 n-tiles
  const int nmt = gridDim.y;                           // 32 m-tiles
  const int nwg = nbx * nmt;
  const int bid = blockIdx.y * nbx + blockIdx.x;
  const int sid = (bid & 7) * (nwg >> 3) + (bid >> 3);
  const int m0 = (sid % nmt) << 6;                     // m fast
  const int n0 = (sid / nmt) << 7;                     // n sliced per XCD
  const int srow = (w << 3) + (l >> 3);
  const int gcol = 8 * ((l & 7) ^ ((srow >> 1) & 7));
  const unsigned short* Ag = A + (size_t)(m0 + srow) * K + gcol;
  const unsigned short* Bg = B + (size_t)(n0 + srow) * K + gcol;
  const size_t r32K = (size_t)32 * K;
  unsigned short* AsW = As + (w << 9);
  unsigned short* BsW = Bs + (w << 9);
  const int cl = l & 15, lh = l >> 4;
  const int fR = (cl >> 1) & 7;
  f32x4 acc[4][2];
  #pragma unroll
  for (int mi = 0; mi < 4; mi++)
    #pragma unroll
    for (int ni = 0; ni < 2; ni++) { f32x4 z = {0.f,0.f,0.f,0.f}; acc[mi][ni] = z; }

  for (int kt = 0; kt < K; kt += 64) {
    gload16(Ag + kt,          AsW);
    gload16(Ag + kt +   r32K, AsW + 2048);
    gload16(Bg + kt,          BsW);
    gload16(Bg + kt +   r32K, BsW + 2048);
    gload16(Bg + kt + 2*r32K, BsW + 4096);
    gload16(Bg + kt + 3*r32K, BsW + 6144);
    __syncthreads();
    #pragma unroll
    for (int kh = 0; kh < 2; kh++) {
      const int so = ((kh * 4 + lh) ^ fR) << 4;
      bf16x8 af[4], bf[2];
      #pragma unroll
      for (int mi = 0; mi < 4; mi++)
        af[mi] = *(const bf16x8*)((const char*)As + (mi*16 + cl) * 128 + so);
      #pragma unroll
      for (int ni = 0; ni < 2; ni++)
        bf[ni] = *(const bf16x8*)((const char*)Bs + (w*16 + ni*64 + cl) * 128 + so);
      #pragma unroll
      for (int mi = 0; mi < 4; mi++)
        #pragma unroll
        for (int ni = 0; ni < 2; ni++)
          acc[mi][ni] = __builtin_amdgcn_mfma_f32_16x16x32_bf16(af[mi], bf[ni], acc[mi][ni], 0, 0, 0);
    }
    __syncthreads();
  }
  const int rbase = lh << 2;
  const int i0 = (w << 4) + cl;                // head-dim pair index 0..63
  const int col_lo = n0 + i0;
  const int reg = n0 >> 11;                    // 0=q, 1=k, 2=v
  const float* lt = nullptr;
  const float* lb_lo = nullptr;
  const float* lb_hi = nullptr;
  if (reg == 0)      { lt = ltq; lb_lo = lbq + (size_t)col_lo * RLORA;
                                 lb_hi = lbq + (size_t)(col_lo + 64) * RLORA; }
  else if (reg == 2) { lt = ltv; lb_lo = lbv + (size_t)(col_lo - 4096) * RLORA;
                                 lb_hi = lbv + (size_t)(col_lo - 4096 + 64) * RLORA; }
  float4 bl0={0,0,0,0}, bl1=bl0, bl2=bl0, bl3=bl0;
  float4 bh0=bl0, bh1=bl0, bh2=bl0, bh3=bl0;
  if (lt) {
    bl0 = ((const float4*)lb_lo)[0]; bl1 = ((const float4*)lb_lo)[1];
    bl2 = ((const float4*)lb_lo)[2]; bl3 = ((const float4*)lb_lo)[3];
    bh0 = ((const float4*)lb_hi)[0]; bh1 = ((const float4*)lb_hi)[1];
    bh2 = ((const float4*)lb_hi)[2]; bh3 = ((const float4*)lb_hi)[3];
  }
  unsigned short* outp = (reg == 0 ? qb : reg == 1 ? kb : vb);
  const int ocol = col_lo - reg * 2048;        // column within q/k/v tensor
  #pragma unroll
  for (int mi = 0; mi < 4; mi++) {
    #pragma unroll
    for (int rr = 0; rr < 4; rr++) {
      int row = m0 + mi * 16 + rbase + rr;
      float lo = acc[mi][0][rr];
      float hi = acc[mi][1][rr];
      if (lt) {
        const float4* tr = (const float4*)(lt + (size_t)row * RLORA);
        float4 t0 = tr[0], t1 = tr[1], t2 = tr[2], t3 = tr[3];
        lo += 2.0f * (t0.x*bl0.x + t0.y*bl0.y + t0.z*bl0.z + t0.w*bl0.w
                    + t1.x*bl1.x + t1.y*bl1.y + t1.z*bl1.z + t1.w*bl1.w
                    + t2.x*bl2.x + t2.y*bl2.y + t2.z*bl2.z + t2.w*bl2.w
                    + t3.x*bl3.x + t3.y*bl3.y + t3.z*bl3.z + t3.w*bl3.w);
        hi += 2.0f * (t0.x*bh0.x + t0.y*bh0.y + t0.z*bh0.z + t0.w*bh0.w
                    + t1.x*bh1.x + t1.y*bh1.y + t1.z*bh1.z + t1.w*bh1.w
                    + t2.x*bh2.x + t2.y*bh2.y + t2.z*bh2.z + t2.w*bh2.w
                    + t3.x*bh3.x + t3.y*bh3.y + t3.z*bh3.z + t3.w*bh3.w);
      }
      if (reg != 2) {                          // RoPE on q and k
        int s = row & (SEQLEN - 1);
        float c = ct[s * 64 + i0], sn = st[s * 64 + i0];
        float nlo = lo * c - hi * sn;
        float nhi = hi * c + lo * sn;
        lo = nlo; hi = nhi;
      }
      outp[(size_t)row * DMODEL + ocol]      = f2b(lo);
      outp[(size_t)row * DMODEL + ocol + 64] = f2b(hi);
    }
  }
}

// ---------------- NT GEMM fallback (B fp32, reg-staged, BK=32) ----------------
template<int MODE>
__global__ __launch_bounds__(256, 2)
void k_gemm(const unsigned short* __restrict__ A, const void* __restrict__ Bv,
            float* __restrict__ Cf, unsigned short* __restrict__ Cb,
            const float* __restrict__ Res, const unsigned short* __restrict__ Gaux,
            int N, int K, int ldc) {
  __shared__ unsigned char lds[128 * 32 * 2 * 2];
  unsigned char* As = lds;
  unsigned char* Bs = lds + 128 * 32 * 2;
  const int t = threadIdx.x;
  const int l = t & 63, w = t >> 6;
  const int wr = w >> 1, wc = w & 1;
  const int m0 = blockIdx.y << 7, n0 = blockIdx.x << 7;
  const int sr = t >> 1, skh = (t & 1) << 4;
  const int sByte = sr * 64 + (skh << 1);
  const int sSwz = (sr & 3) << 4;
  const unsigned short* Ap = A + (size_t)(m0 + sr) * K + skh;
  const float* Bp32 = (const float*)Bv + (size_t)(n0 + sr) * K + skh;
  const int kOff = (((l >> 4) << 4)) ^ ((l & 3) << 4);
  const int arow = wr * 64 + (l & 15);
  const int brow = wc * 64 + (l & 15);
  f32x4 acc[4][4];
  #pragma unroll
  for (int mi = 0; mi < 4; mi++)
    #pragma unroll
    for (int ni = 0; ni < 4; ni++) { f32x4 z = {0.f,0.f,0.f,0.f}; acc[mi][ni] = z; }

  for (int kt = 0; kt < K; kt += 32) {
    uint4 a0 = *(const uint4*)(Ap + kt);
    uint4 a1 = *(const uint4*)(Ap + kt + 8);
    *(uint4*)(As + ((sByte)      ^ sSwz)) = a0;
    *(uint4*)(As + ((sByte + 16) ^ sSwz)) = a1;
    float4 f0 = *(const float4*)(Bp32 + kt);
    float4 f1 = *(const float4*)(Bp32 + kt + 4);
    float4 f2 = *(const float4*)(Bp32 + kt + 8);
    float4 f3 = *(const float4*)(Bp32 + kt + 12);
    us8 q0, q1;
    q0[0]=f2b(f0.x); q0[1]=f2b(f0.y); q0[2]=f2b(f0.z); q0[3]=f2b(f0.w);
    q0[4]=f2b(f1.x); q0[5]=f2b(f1.y); q0[6]=f2b(f1.z); q0[7]=f2b(f1.w);
    q1[0]=f2b(f2.x); q1[1]=f2b(f2.y); q1[2]=f2b(f2.z); q1[3]=f2b(f2.w);
    q1[4]=f2b(f3.x); q1[5]=f2b(f3.y); q1[6]=f2b(f3.z); q1[7]=f2b(f3.w);
    *(us8*)(Bs + ((sByte)      ^ sSwz)) = q0;
    *(us8*)(Bs + ((sByte + 16) ^ sSwz)) = q1;
    __syncthreads();
    bf16x8 af[4], bfr[4];
    #pragma unroll
    for (int i = 0; i < 4; i++) {
      af[i]  = *(const bf16x8*)(As + (arow + 16 * i) * 64 + kOff);
      bfr[i] = *(const bf16x8*)(Bs + (brow + 16 * i) * 64 + kOff);
    }
    #pragma unroll
    for (int mi = 0; mi < 4; mi++)
      #pragma unroll
      for (int ni = 0; ni < 4; ni++)
        acc[mi][ni] = __builtin_amdgcn_mfma_f32_16x16x32_bf16(af[mi], bfr[ni], acc[mi][ni], 0, 0, 0);
    __syncthreads();
  }
  const int rbase = (l >> 4) << 2;
  const int cl = l & 15;
  #pragma unroll
  for (int mi = 0; mi < 4; mi++) {
    #pragma unroll
    for (int ni = 0; ni < 4; ni++) {
      #pragma unroll
      for (int rr = 0; rr < 4; rr++) {
        int row = m0 + wr * 64 + mi * 16 + rbase + rr;
        int col = n0 + wc * 64 + ni * 16 + cl;
        size_t idx = (size_t)row * ldc + col;
        float val = acc[mi][ni][rr];
        if constexpr (MODE == 0) Cf[idx] = val;
        if constexpr (MODE == 1) Cf[idx] = val + Res[idx];
        if constexpr (MODE == 2) Cb[idx] = f2b(val);
        if constexpr (MODE == 3) {
          float gv = b2f(Gaux[idx]);
          val *= gv / (1.0f + __expf(-gv));
          Cb[idx] = f2b(val);
        }
      }
    }
  }
}

// ---------------- merged LoRA down: tbq/tbv = h Aq^T / h Av^T ----------------
__global__ void k_lora_down2(const unsigned short* __restrict__ h,
                             const float* __restrict__ Aq, const float* __restrict__ Av,
                             float* __restrict__ tbq, float* __restrict__ tbv) {
  int t = threadIdx.x;
  int m = blockIdx.x * 8 + (t >> 5), r = t & 31;
  const float* ar = (r < 16) ? (Aq + (size_t)r * DMODEL)
                             : (Av + (size_t)(r - 16) * DMODEL);
  const unsigned short* hr = h + (size_t)m * DMODEL;
  float acc = 0.f;
  for (int d = 0; d < DMODEL; d += 4) {
    ushort4 hv = *(const ushort4*)(hr + d);
    float4 av = *(const float4*)(ar + d);
    acc += b2f(hv.x)*av.x + b2f(hv.y)*av.y + b2f(hv.z)*av.z + b2f(hv.w)*av.w;
  }
  if (r < 16) tbq[(size_t)m * RLORA + r] = acc;
  else        tbv[(size_t)m * RLORA + (r - 16)] = acc;
}

// fallback lora kernels (fp32 path only)
__global__ void k_lora_down(const unsigned short* __restrict__ h, const float* __restrict__ Am,
                            float* __restrict__ tb) {
  int t = threadIdx.x;
  int m = blockIdx.x * 16 + (t >> 4), r = t & 15;
  const unsigned short* hr = h + (size_t)m * DMODEL;
  const float* ar = Am + (size_t)r * DMODEL;
  float acc = 0.f;
  for (int d = 0; d < DMODEL; d += 4) {
    ushort4 hv = *(const ushort4*)(hr + d);
    float4 av = *(const float4*)(ar + d);
    acc += b2f(hv.x)*av.x + b2f(hv.y)*av.y + b2f(hv.z)*av.z + b2f(hv.w)*av.w;
  }
  tb[(size_t)m * RLORA + r] = acc;
}

__global__ void k_lora_up(const float* __restrict__ tb, const float* __restrict__ Bm,
                          float* __restrict__ out, int ldc) {
  int tid = blockIdx.x * 256 + threadIdx.x;
  int m = tid >> 11, e = tid & (DMODEL - 1);
  const float* tr = tb + (size_t)m * RLORA;
  const float* br = Bm + (size_t)e * RLORA;
  float acc = 0.f;
  #pragma unroll
  for (int r = 0; r < RLORA; r += 4) {
    float4 tv = *(const float4*)(tr + r);
    float4 bv = *(const float4*)(br + r);
    acc += tv.x*bv.x + tv.y*bv.y + tv.z*bv.z + tv.w*bv.w;
  }
  out[(size_t)m * ldc + e] += 2.0f * acc;
}

// ---------------- RoPE tables ----------------
__global__ void k_rope_table(float* __restrict__ ct, float* __restrict__ st) {
  int tid = blockIdx.x * 256 + threadIdx.x;
  int s = tid >> 6, i = tid & 63;
  float inv = __expf(-((float)i / 64.0f) * logf(10000.0f));
  float ang = (float)s * inv;
  ct[tid] = cosf(ang);
  st[tid] = sinf(ang);
}

// fallback rope (f32 qkv -> qb, kb, vb dense)
__global__ void k_rope2(const float* __restrict__ qkv,
                        const float* __restrict__ ct, const float* __restrict__ st,
                        unsigned short* __restrict__ qb, unsigned short* __restrict__ kb,
                        unsigned short* __restrict__ vb) {
  int tid = blockIdx.x * 256 + threadIdx.x;
  int i = tid & 63;
  int hh = (tid >> 6) & (NHEAD - 1);
  int s = (tid >> 10) & (SEQLEN - 1);
  int b = tid >> 20;
  size_t ibase = ((size_t)(b * SEQLEN + s)) * QKVS + hh * HEADD;
  size_t obase = ((size_t)(b * SEQLEN + s)) * DMODEL + hh * HEADD;
  float c = ct[s * 64 + i], sn = st[s * 64 + i];
  float q0 = qkv[ibase + i], q1 = qkv[ibase + i + 64];
  qb[obase + i]      = f2b(q0 * c - q1 * sn);
  qb[obase + i + 64] = f2b(q1 * c + q0 * sn);
  float k0 = qkv[ibase + 2048 + i], k1 = qkv[ibase + 2048 + i + 64];
  kb[obase + i]      = f2b(k0 * c - k1 * sn);
  kb[obase + i + 64] = f2b(k1 * c + k0 * sn);
  vb[obase + i]      = f2b(qkv[ibase + 4096 + i]);
  vb[obase + i + 64] = f2b(qkv[ibase + 4096 + i + 64]);
}

// ---------------- fused causal attention, MFMA bf16 inputs ----------------
// T14 async-STAGE: K/V tile kb+1 prefetched into registers AFTER barrier B.
__global__ __launch_bounds__(256, 2)
void k_attn_bf16(const unsigned short* __restrict__ qbp, const unsigned short* __restrict__ kbp,
                 const unsigned short* __restrict__ vbp, const int* __restrict__ am,
                 unsigned short* __restrict__ o, int vstride) {
  __shared__ unsigned char Kls[64 * 256];
  __shared__ unsigned char Vls[128 * 128];
  __shared__ unsigned char Pls[64 * 128];
  const int qt = blockIdx.x, hh = blockIdx.y, b = blockIdx.z;
  const int t = threadIdx.x, l = t & 63, w = t >> 6;
  const int cl = l & 15, lh = l >> 4;
  const int rbase = lh << 2;
  const int prow = t >> 4;
  const int pc   = t & 15;

  #pragma unroll
  for (int ii = 0; ii < 4; ii++) {
    int row = prow + 16 * ii;
    uint4 u = *(const uint4*)(qbp + ((size_t)(b*SEQLEN + qt*64 + row)) * DMODEL + hh * HEADD + pc * 8);
    *(uint4*)(Kls + ((row * 256 + pc * 16) ^ ((row & 7) << 4))) = u;
  }
  uint4 kreg[4], vreg[4];
  #pragma unroll
  for (int ii = 0; ii < 4; ii++) {
    int row = prow + 16 * ii;
    kreg[ii] = *(const uint4*)(kbp + ((size_t)(b*SEQLEN + row)) * DMODEL + hh * HEADD + pc * 8);
    vreg[ii] = *(const uint4*)(vbp + ((size_t)(b*SEQLEN + row)) * vstride + hh * HEADD + pc * 8);
  }
  __syncthreads();
  bf16x8 qf[4];
  {
    int row = w * 16 + cl;
    int swz = (row & 7) << 4;
    #pragma unroll
    for (int kt = 0; kt < 4; kt++)
      qf[kt] = *(const bf16x8*)(Kls + ((row * 256 + kt * 64 + lh * 16) ^ swz));
  }

  f32x4 oacc[8];
  #pragma unroll
  for (int i = 0; i < 8; i++) { f32x4 z = {0.f,0.f,0.f,0.f}; oacc[i] = z; }
  float mrun[4], lrun[4];
  #pragma unroll
  for (int r = 0; r < 4; r++) { mrun[r] = -3e38f; lrun[r] = 0.f; }

  for (int kb = 0; kb <= qt; kb++) {
    __syncthreads();
    #pragma unroll
    for (int ii = 0; ii < 4; ii++) {
      int row = prow + 16 * ii;
      *(uint4*)(Kls + ((row * 256 + pc * 16) ^ ((row & 7) << 4))) = kreg[ii];
    }
    #pragma unroll
    for (int ii = 0; ii < 4; ii++) {
      int n = prow + 16 * ii;
      uint4 a = vreg[ii];
      uint4 p;
      p.x = __shfl_xor(a.x, 16); p.y = __shfl_xor(a.y, 16);
      p.z = __shfl_xor(a.z, 16); p.w = __shfl_xor(a.w, 16);
      if (!(l & 16)) {
        int d0 = pc * 8, nb = n * 2;
        unsigned int wd[8];
        wd[0] = (a.x & 0xffffu) | (p.x << 16);
        wd[1] = (a.x >> 16)     | (p.x & 0xffff0000u);
        wd[2] = (a.y & 0xffffu) | (p.y << 16);
        wd[3] = (a.y >> 16)     | (p.y & 0xffff0000u);
        wd[4] = (a.z & 0xffffu) | (p.z << 16);
        wd[5] = (a.z >> 16)     | (p.z & 0xffff0000u);
        wd[6] = (a.w & 0xffffu) | (p.w << 16);
        wd[7] = (a.w >> 16)     | (p.w & 0xffff0000u);
        #pragma unroll
        for (int e = 0; e < 8; e++)
          *(unsigned int*)(Vls + (((d0 + e) * 128 + nb) ^ vswz(d0 + e))) = wd[e];
      }
    }
    __syncthreads();
    if (kb < qt) {
      #pragma unroll
      for (int ii = 0; ii < 4; ii++) {
        int row = prow + 16 * ii;
        kreg[ii] = *(const uint4*)(kbp + ((size_t)(b*SEQLEN + (kb+1)*64 + row)) * DMODEL + hh * HEADD + pc * 8);
        vreg[ii] = *(const uint4*)(vbp + ((size_t)(b*SEQLEN + (kb+1)*64 + row)) * vstride + hh * HEADD + pc * 8);
      }
    }
    f32x4 sacc[4];
    #pragma unroll
    for (int nt = 0; nt < 4; nt++) { f32x4 z = {0.f,0.f,0.f,0.f}; sacc[nt] = z; }
    #pragma unroll
    for (int kt = 0; kt < 4; kt++) {
      #pragma unroll
      for (int nt = 0; nt < 4; nt++) {
        int row = nt * 16 + cl;
        bf16x8 kf = *(const bf16x8*)(Kls + ((row * 256 + kt * 64 + lh * 16) ^ ((row & 7) << 4)));
        sacc[nt] = __builtin_amdgcn_mfma_f32_16x16x32_bf16(qf[kt], kf, sacc[nt], 0, 0, 0);
      }
    }
    float p[4][4];
    float mt[4] = {-3e38f, -3e38f, -3e38f, -3e38f};
    #pragma unroll
    for (int nt = 0; nt < 4; nt++) {
      int kg = kb * 64 + nt * 16 + cl;
      float pad = (1.0f - (float)am[b * SEQLEN + kg]) * (-1e9f);
      #pragma unroll
      for (int r = 0; r < 4; r++) {
        int qg = qt * 64 + w * 16 + rbase + r;
        float s = sacc[nt][r] * 0.08838834764831845f + pad;
        if (kg > qg) s = -1e30f;
        p[nt][r] = s;
        mt[r] = fmaxf(mt[r], s);
      }
    }
    #pragma unroll
    for (int r = 0; r < 4; r++) {
      float m = mt[r];
      m = fmaxf(m, __shfl_xor(m, 1)); m = fmaxf(m, __shfl_xor(m, 2));
      m = fmaxf(m, __shfl_xor(m, 4)); m = fmaxf(m, __shfl_xor(m, 8));
      mt[r] = m;
    }
    float corr[4];
    #pragma unroll
    for (int r = 0; r < 4; r++) {
      float mnew = fmaxf(mrun[r], mt[r]);
      corr[r] = __expf(mrun[r] - mnew);
      mrun[r] = mnew;
    }
    float ps[4] = {0.f, 0.f, 0.f, 0.f};
    #pragma unroll
    for (int nt = 0; nt < 4; nt++)
      #pragma unroll
      for (int r = 0; r < 4; r++) {
        p[nt][r] = __expf(p[nt][r] - mrun[r]);
        ps[r] += p[nt][r];
      }
    #pragma unroll
    for (int r = 0; r < 4; r++) {
      float s = ps[r];
      s += __shfl_xor(s, 1); s += __shfl_xor(s, 2);
      s += __shfl_xor(s, 4); s += __shfl_xor(s, 8);
      lrun[r] = lrun[r] * corr[r] + s;
    }
    #pragma unroll
    for (int nt = 0; nt < 4; nt++)
      #pragma unroll
      for (int r = 0; r < 4; r++) {
        int row = w * 16 + rbase + r;
        *(unsigned short*)(Pls + ((row * 128 + (nt * 16 + cl) * 2) ^ ((row & 7) << 4))) = f2b(p[nt][r]);
      }
    #pragma unroll
    for (int dt = 0; dt < 8; dt++)
      #pragma unroll
      for (int r = 0; r < 4; r++) oacc[dt][r] *= corr[r];
    {
      int prw = w * 16 + cl, pswz = (prw & 7) << 4;
      bf16x8 pf0 = *(const bf16x8*)(Pls + ((prw * 128 +  0 + lh * 16) ^ pswz));
      bf16x8 pf1 = *(const bf16x8*)(Pls + ((prw * 128 + 64 + lh * 16) ^ pswz));
      #pragma unroll
      for (int dt = 0; dt < 8; dt++) {
        int drow = dt * 16 + cl;
        bf16x8 vf0 = *(const bf16x8*)(Vls + ((drow * 128 +  0 + lh * 16) ^ vswz(drow)));
        bf16x8 vf1 = *(const bf16x8*)(Vls + ((drow * 128 + 64 + lh * 16) ^ vswz(drow)));
        oacc[dt] = __builtin_amdgcn_mfma_f32_16x16x32_bf16(pf0, vf0, oacc[dt], 0, 0, 0);
        oacc[dt] = __builtin_amdgcn_mfma_f32_16x16x32_bf16(pf1, vf1, oacc[dt], 0, 0, 0);
      }
    }
  }
  size_t obase = (((size_t)b * SEQLEN + qt * 64 + w * 16) * NHEAD + hh) * HEADD;
  #pragma unroll
  for (int r = 0; r < 4; r++) {
    float inv = 1.0f / lrun[r];
    int row = rbase + r;
    #pragma unroll
    for (int dt = 0; dt < 8; dt++)
      o[obase + (size_t)row * (NHEAD * HEADD) + dt * 16 + cl] = f2b(oacc[dt][r] * inv);
  }
}

// ---------------- pooling + final RMS ----------------
__global__ void k_pool(const float* __restrict__ x, const int* __restrict__ am,
                       const float* __restrict__ fn, float* __restrict__ pooled) {
  int b = blockIdx.x, t = threadIdx.x;
  __shared__ float red[4];
  float fc = 0.f;
  for (int i = t; i < SEQLEN; i += 256) fc += (float)am[b * SEQLEN + i];
  for (int m = 32; m; m >>= 1) fc += __shfl_xor(fc, m);
  if ((t & 63) == 0) red[t >> 6] = fc;
  __syncthreads();
  int idx = (int)(red[0] + red[1] + red[2] + red[3]) - 1;
  const float* xr = x + ((size_t)b * SEQLEN + idx) * DMODEL;
  float4 a = ((const float4*)xr)[t], c = ((const float4*)xr)[t + 256];
  float ss = a.x*a.x + a.y*a.y + a.z*a.z + a.w*a.w
           + c.x*c.x + c.y*c.y + c.z*c.z + c.w*c.w;
  for (int m = 32; m; m >>= 1) ss += __shfl_xor(ss, m);
  __syncthreads();
  if ((t & 63) == 0) red[t >> 6] = ss;
  __syncthreads();
  ss = red[0] + red[1] + red[2] + red[3];
  float rs = rsqrtf(ss * (1.0f / DMODEL) + 1e-5f);
  float4 w0 = ((const float4*)fn)[t], w1 = ((const float4*)fn)[t + 256];
  float4 o0, o1;
  o0.x = a.x*rs*w0.x; o0.y = a.y*rs*w0.y; o0.z = a.z*rs*w0.z; o0.w = a.w*rs*w0.w;
  o1.x = c.x*rs*w1.x; o1.y = c.y*rs*w1.y; o1.z = c.z*rs*w1.z; o1.w = c.w*rs*w1.w;
  ((float4*)(pooled + (size_t)b * DMODEL))[t] = o0;
  ((float4*)(pooled + (size_t)b * DMODEL))[t + 256] = o1;
}

// ---------------- classification head ----------------
__global__ void k_head1(const float* __restrict__ pooled, const float* __restrict__ W1,
                        const float* __restrict__ b1, float* __restrict__ h1) {
  int bi = blockIdx.x;
  int b = bi >> 3, e = ((bi & 7) << 8) + threadIdx.x;
  const float* pr = pooled + (size_t)b * DMODEL;
  const float* wr = W1 + (size_t)e * DMODEL;
  float acc = 0.f;
  for (int d = 0; d < DMODEL; d += 4) {
    float4 pv = *(const float4*)(pr + d);
    float4 wv = *(const float4*)(wr + d);
    acc += pv.x*wv.x + pv.y*wv.y + pv.z*wv.z + pv.w*wv.w;
  }
  h1[(size_t)b * DMODEL + e] = tanhf(acc + b1[e]);
}

__global__ void k_head2(const float* __restrict__ h1, const float* __restrict__ W2,
                        const float* __restrict__ b2, float* __restrict__ out) {
  int bi = blockIdx.x;
  int b = bi / 3, c = bi % 3;
  int l = threadIdx.x;
  float acc = 0.f;
  for (int e = l; e < DMODEL; e += 64)
    acc += h1[(size_t)b * DMODEL + e] * W2[(size_t)c * DMODEL + e];
  for (int m = 32; m; m >>= 1) acc += __shfl_xor(acc, m);
  if (l == 0) out[b * 3 + c] = acc + b2[c];
}

__global__ void k_sentinel(float* out) {
  if (threadIdx.x < 6) out[threadIdx.x] = -12345.0f;
}

// ---------------- launch ----------------
extern "C" void kernel_launch(void* const* d_in, const int* in_sizes, int n_in,
                              void* d_out, int out_size, void* d_ws, size_t ws_size,
                              hipStream_t stream) {
  const int*   ids = (const int*)d_in[0];
  const int*   am  = (const int*)d_in[1];
  const float* emb = (const float*)d_in[2];
  const float* Wq  = (const float*)d_in[3];
  const float* Wk  = (const float*)d_in[4];
  const float* Wv  = (const float*)d_in[5];
  const float* Wo  = (const float*)d_in[6];
  const float* Aq  = (const float*)d_in[7];
  const float* Bq  = (const float*)d_in[8];
  const float* Av  = (const float*)d_in[9];
  const float* Bv  = (const float*)d_in[10];
  const float* Wg  = (const float*)d_in[11];
  const float* Wu  = (const float*)d_in[12];
  const float* Wd  = (const float*)d_in[13];
  const float* n1  = (const float*)d_in[14];
  const float* n2  = (const float*)d_in[15];
  const float* fn  = (const float*)d_in[16];
  const float* hW1 = (const float*)d_in[17];
  const float* hb1 = (const float*)d_in[18];
  const float* hW2 = (const float*)d_in[19];
  const float* hb2 = (const float*)d_in[20];
  float* out = (float*)d_out;

  // workspace layout
  const size_t XOFF    = 0;                       // x f32 16MB
  const size_t HOFF    = 16777216;                // h bf16 8MB
  const size_t QBOFF   = 25165824;                // qb bf16 8MB
  const size_t KBOFF   = 33554432;                // kb bf16 8MB
  const size_t VBOFF   = 41943040;                // vb bf16 8MB
  const size_t OOFF    = 50331648;                // o bf16 8MB
  const size_t GOFF    = 58720256;                // g bf16 32MB
  const size_t ACTOFF  = 92274688;                // act bf16 32MB
  const size_t QKV32OFF= 125829120;               // qkv f32 48MB (fallback only)
  const size_t TOFF    = 176160768;               // tails
  const size_t NEED = TOFF + 131072 + 131072 + 262144 + 262144 + 16384 + 16384;
  if (ws_size < NEED) {
    k_sentinel<<<1, 64, 0, stream>>>(out);
    return;
  }
  const size_t W16OFF   = (NEED + 255) & ~(size_t)255;
  const size_t W16BYTES = 536870912ull;
  const bool   use16    = ws_size >= W16OFF + W16BYTES;

  char* ws = (char*)d_ws;
  float*          x     = (float*)(ws + XOFF);
  unsigned short* h     = (unsigned short*)(ws + HOFF);
  unsigned short* qb    = (unsigned short*)(ws + QBOFF);
  unsigned short* kb    = (unsigned short*)(ws + KBOFF);
  unsigned short* vb    = (unsigned short*)(ws + VBOFF);
  unsigned short* o     = (unsigned short*)(ws + OOFF);
  unsigned short* g     = (unsigned short*)(ws + GOFF);
  unsigned short* act   = (unsigned short*)(ws + ACTOFF);
  float*          qkv32 = (float*)(ws + QKV32OFF);
  float* tbq    = (float*)(ws + TOFF);
  float* tbv    = (float*)(ws + TOFF + 131072);
  float* ct     = (float*)(ws + TOFF + 262144);
  float* st     = (float*)(ws + TOFF + 262144 + 262144);
  float* pooled = (float*)(ws + TOFF + 262144 + 524288);
  float* h1     = (float*)(ws + TOFF + 262144 + 524288 + 16384);

  unsigned short* w16 = (unsigned short*)(ws + W16OFF);
  const size_t DD = (size_t)DMODEL * DMODEL;      // 4M elems
  const size_t FD = (size_t)FFDIM * DMODEL;       // 16M elems
  unsigned short* wqkv16 = w16;                              // L*3*DD
  unsigned short* wo16   = w16 + 4ull * 3 * DD;              // L*DD
  unsigned short* wg16   = wo16 + 4ull * DD;                 // L*FD
  unsigned short* wu16   = wg16 + 4ull * FD;
  unsigned short* wd16   = wu16 + 4ull * FD;
  if (use16) {
    k_cvtqkv<<<2048, 256, 0, stream>>>(Wq, Wk, Wv, wqkv16);
    k_cvt16<<<2048, 256, 0, stream>>>(Wo, wo16, (int)(4 * DD / 8));
    k_cvt16<<<2048, 256, 0, stream>>>(Wg, wg16, (int)(4 * FD / 8));
    k_cvt16<<<2048, 256, 0, stream>>>(Wu, wu16, (int)(4 * FD / 8));
    k_cvt16<<<2048, 256, 0, stream>>>(Wd, wd16, (int)(4 * FD / 8));
  }

  k_embed<<<NTOK, 256, 0, stream>>>(ids, emb, x);
  k_rope_table<<<SEQLEN * 64 / 256, 256, 0, stream>>>(ct, st);

  dim3 g16(16, 16), gqkv(48, 32), gff8(32, 8), gsq(16, 32), ga(SEQLEN / 64, NHEAD, NBATCH);
  for (int lay = 0; lay < NLAYER; lay++) {
    const float* Bq_l = Bq + (size_t)lay * DMODEL * RLORA;
    const float* Bv_l = Bv + (size_t)lay * DMODEL * RLORA;
    k_rmsnorm<<<NTOK, 256, 0, stream>>>(x, n1 + (size_t)lay * DMODEL, h);
    if (use16) {
      k_lora_down2<<<NTOK / 8, 256, 0, stream>>>(h, Aq + (size_t)lay * RLORA * DMODEL,
                                                 Av + (size_t)lay * RLORA * DMODEL, tbq, tbv);
      // QKV GEMM + fused LoRA + fused RoPE -> qb/kb/vb bf16 directly
      k_gemm7<<<gqkv, 256, 0, stream>>>(h, wqkv16 + lay*3*DD, qb, kb, vb, ct, st,
                                        DMODEL, tbq, tbv, Bq_l, Bv_l);
      k_attn_bf16<<<ga, 256, 0, stream>>>(qb, kb, vb, am, o, DMODEL);
      // Wo: 64x128 tile BK=128, 2D XCD chunking
      k_gemm6<1><<<gsq, 256, 0, stream>>>(o, wo16 + lay*DD, x, nullptr, x, nullptr, DMODEL, DMODEL, DMODEL);
      k_rmsnorm<<<NTOK, 256, 0, stream>>>(x, n2 + (size_t)lay * DMODEL, h);
      // FFN: 8-phase 256^2 GEMMs; g then u (u epilogue applies silu(g)*u)
      k_gemm8<2><<<gff8, 512, 0, stream>>>(h, wg16 + lay*FD, g,   nullptr, FFDIM, DMODEL, FFDIM);
      k_gemm8<3><<<gff8, 512, 0, stream>>>(h, wu16 + lay*FD, act, g,       FFDIM, DMODEL, FFDIM);
      // Wd: 64x128 tile BK=128, K=8192
      k_gemm6<1><<<gsq, 256, 0, stream>>>(act, wd16 + lay*FD, x, nullptr, x, nullptr, DMODEL, FFDIM, DMODEL);
    } else {
      k_lora_down<<<NTOK / 16, 256, 0, stream>>>(h, Aq + (size_t)lay * RLORA * DMODEL, tbq);
      k_lora_down<<<NTOK / 16, 256, 0, stream>>>(h, Av + (size_t)lay * RLORA * DMODEL, tbv);
      k_gemm<0><<<g16, 256, 0, stream>>>(h, Wq + lay*DD, qkv32,        nullptr, nullptr, nullptr, DMODEL, DMODEL, QKVS);
      k_gemm<0><<<g16, 256, 0, stream>>>(h, Wk + lay*DD, qkv32 + 2048, nullptr, nullptr, nullptr, DMODEL, DMODEL, QKVS);
      k_gemm<0><<<g16, 256, 0, stream>>>(h, Wv + lay*DD, qkv32 + 4096, nullptr, nullptr, nullptr, DMODEL, DMODEL, QKVS);
      k_lora_up<<<NTOK * DMODEL / 256, 256, 0, stream>>>(tbq, Bq_l, qkv32, QKVS);
      k_lora_up<<<NTOK * DMODEL / 256, 256, 0, stream>>>(tbv, Bv_l, qkv32 + 4096, QKVS);
      k_rope2<<<NBATCH * SEQLEN * NHEAD * 64 / 256, 256, 0, stream>>>(qkv32, ct, st, qb, kb, vb);
      k_attn_bf16<<<ga, 256, 0, stream>>>(qb, kb, vb, am, o, DMODEL);
      k_gemm<1><<<g16, 256, 0, stream>>>(o, Wo + lay*DD, x, nullptr, x, nullptr, DMODEL, DMODEL, DMODEL);
      k_rmsnorm<<<NTOK, 256, 0, stream>>>(x, n2 + (size_t)lay * DMODEL, h);
      k_gemm<2><<<dim3(64,16), 256, 0, stream>>>(h, Wg + lay*FD, nullptr, g, nullptr, nullptr, FFDIM, DMODEL, FFDIM);
      k_gemm<3><<<dim3(64,16), 256, 0, stream>>>(h, Wu + lay*FD, nullptr, act, nullptr, g, FFDIM, DMODEL, FFDIM);
      k_gemm<1><<<g16, 256, 0, stream>>>(act, Wd + lay*FD, x, nullptr, x, nullptr, DMODEL, FFDIM, DMODEL);
    }
  }
  k_pool<<<NBATCH, 256, 0, stream>>>(x, am, fn, pooled);
  k_head1<<<16, 256, 0, stream>>>(pooled, hW1, hb1, h1);
  k_head2<<<6, 64, 0, stream>>>(h1, hW2, hb2, out);
}

// Round 17
// 2505.226 us; speedup vs baseline: 1.0644x; 1.0644x over previous
//
#include <hip/hip_runtime.h>

// ---------------- model constants ----------------
#define NLAYER 4
#define DMODEL 2048
#define NHEAD  16
#define HEADD  128
#define FFDIM  8192
#define RLORA  16
#define SEQLEN 1024
#define NBATCH 2
#define NTOK   (NBATCH*SEQLEN)   // 2048
#define QKVS   6144              // fused qkv row stride

typedef __bf16 bf16x8 __attribute__((ext_vector_type(8)));
typedef float  f32x4  __attribute__((ext_vector_type(4)));
typedef unsigned short us8 __attribute__((ext_vector_type(8)));

__device__ __forceinline__ unsigned short f2b(float f) {
  unsigned int u = __builtin_bit_cast(unsigned int, f);
  u += 0x7FFFu + ((u >> 16) & 1u);          // round-to-nearest-even
  return (unsigned short)(u >> 16);
}
__device__ __forceinline__ float b2f(unsigned short s) {
  unsigned int u = ((unsigned int)s) << 16;
  return __builtin_bit_cast(float, u);
}
// V-LDS swizzle for attention
__device__ __forceinline__ int vswz(int d) {
  return (((d >> 2) & 7) ^ ((d & 3) << 1)) << 4;
}
typedef __attribute__((address_space(1))) const void* gas_t;
typedef __attribute__((address_space(3))) void* las_t;
__device__ __forceinline__ void gload16(const void* g, void* l) {
  __builtin_amdgcn_global_load_lds((gas_t)g, (las_t)l, 16, 0, 0);
}

// ---------------- embedding gather ----------------
__global__ void k_embed(const int* __restrict__ ids, const float* __restrict__ emb,
                        float* __restrict__ x) {
  int row = blockIdx.x;
  int id = ids[row];
  const float4* src = (const float4*)(emb + (size_t)id * DMODEL);
  float4* dst = (float4*)(x + (size_t)row * DMODEL);
  for (int i = threadIdx.x; i < DMODEL / 4; i += 256) dst[i] = src[i];
}

// ---------------- weight fp32 -> bf16 (branch-free) ----------------
__global__ void k_cvt16(const float* __restrict__ s, unsigned short* __restrict__ d, int n8) {
  int stride = gridDim.x * 256;
  for (int i = blockIdx.x * 256 + threadIdx.x; i < n8; i += stride) {
    size_t si = (size_t)i * 2;
    float4 a = ((const float4*)s)[si];
    float4 b = ((const float4*)s)[si + 1];
    us8 o;
    o[0]=f2b(a.x); o[1]=f2b(a.y); o[2]=f2b(a.z); o[3]=f2b(a.w);
    o[4]=f2b(b.x); o[5]=f2b(b.y); o[6]=f2b(b.z); o[7]=f2b(b.w);
    ((us8*)d)[i] = o;
  }
}

// merged Q/K/V conversion: dst layout per layer = [Wq | Wk | Wv]
__global__ void k_cvtqkv(const float* __restrict__ Wq, const float* __restrict__ Wk,
                         const float* __restrict__ Wv, unsigned short* __restrict__ d) {
  const size_t DD8 = (size_t)DMODEL * DMODEL / 8;      // 2^19
  const int n8 = (int)(NLAYER * 3 * DD8);
  int stride = gridDim.x * 256;
  for (int i = blockIdx.x * 256 + threadIdx.x; i < n8; i += stride) {
    int blk = i >> 19;
    int lay = blk / 3;
    int ten = blk - lay * 3;
    int off = i & ((1 << 19) - 1);
    const float* s = (ten == 0 ? Wq : ten == 1 ? Wk : Wv) + (size_t)lay * DMODEL * DMODEL;
    float4 a = ((const float4*)s)[(size_t)off * 2];
    float4 b = ((const float4*)s)[(size_t)off * 2 + 1];
    us8 o;
    o[0]=f2b(a.x); o[1]=f2b(a.y); o[2]=f2b(a.z); o[3]=f2b(a.w);
    o[4]=f2b(b.x); o[5]=f2b(b.y); o[6]=f2b(b.z); o[7]=f2b(b.w);
    ((us8*)(d))[(size_t)i] = o;
  }
}

// ---------------- RMSNorm -> bf16 ----------------
__global__ void k_rmsnorm(const float* __restrict__ x, const float* __restrict__ w,
                          unsigned short* __restrict__ h) {
  int row = blockIdx.x, t = threadIdx.x;
  const float* xr = x + (size_t)row * DMODEL;
  float4 a = ((const float4*)xr)[t];
  float4 b = ((const float4*)xr)[t + 256];
  float ss = a.x*a.x + a.y*a.y + a.z*a.z + a.w*a.w
           + b.x*b.x + b.y*b.y + b.z*b.z + b.w*b.w;
  for (int m = 32; m; m >>= 1) ss += __shfl_xor(ss, m);
  __shared__ float red[4];
  if ((t & 63) == 0) red[t >> 6] = ss;
  __syncthreads();
  ss = red[0] + red[1] + red[2] + red[3];
  float rs = rsqrtf(ss * (1.0f / DMODEL) + 1e-5f);
  float4 wa = ((const float4*)w)[t];
  float4 wb = ((const float4*)w)[t + 256];
  ushort4 oa, ob;
  oa.x = f2b(a.x * wa.x * rs); oa.y = f2b(a.y * wa.y * rs);
  oa.z = f2b(a.z * wa.z * rs); oa.w = f2b(a.w * wa.w * rs);
  ob.x = f2b(b.x * wb.x * rs); ob.y = f2b(b.y * wb.y * rs);
  ob.z = f2b(b.z * wb.z * rs); ob.w = f2b(b.w * wb.w * rs);
  ushort4* hr = (ushort4*)(h + (size_t)row * DMODEL);
  hr[t] = oa;
  hr[t + 256] = ob;
}

// ============ fused FFN gate+up: act = bf16(silu(A·Wg^T) * (A·Wu^T)) ============
__global__ __launch_bounds__(512, 4)
void k_ffn(const unsigned short* __restrict__ A, const unsigned short* __restrict__ Bgw,
           const unsigned short* __restrict__ Buw, unsigned short* __restrict__ act,
           int N, int K, int ldc) {
  __shared__ unsigned short As[8192];    // 128 x 64  16KB
  __shared__ unsigned short Gs[8192];
  __shared__ unsigned short Us[8192];
  const int t = threadIdx.x, l = t & 63, w = t >> 6;   // 8 waves
  const int wm = w >> 2, wn = w & 3;                    // 2M x 4N
  const int nbx = gridDim.x;
  const int nmt = gridDim.y;                            // m tiles (16)
  const int nwg = nbx * nmt;
  const int bid = blockIdx.y * nbx + blockIdx.x;
  const int sid = (bid & 7) * (nwg >> 3) + (bid >> 3);  // XCD-contiguous
  const int m0 = (sid % nmt) << 7;                      // m fast
  const int n0 = (sid / nmt) << 7;                      // n sliced per XCD
  const int srow = (w << 3) + (l >> 3);
  const int gcol = 8 * ((l & 7) ^ ((srow >> 1) & 7));
  const unsigned short* Ap = A   + (size_t)(m0 + srow) * K + gcol;
  const unsigned short* Gp = Bgw + (size_t)(n0 + srow) * K + gcol;
  const unsigned short* Up = Buw + (size_t)(n0 + srow) * K + gcol;
  const size_t r64K = (size_t)64 * K;
  unsigned short* AsW = As + (w << 9);
  unsigned short* GsW = Gs + (w << 9);
  unsigned short* UsW = Us + (w << 9);
  const int cl = l & 15, lh = l >> 4;
  const int fR = (cl >> 1) & 7;
  f32x4 ag[4][2], au[4][2];
  #pragma unroll
  for (int mi = 0; mi < 4; mi++)
    #pragma unroll
    for (int ni = 0; ni < 2; ni++) {
      f32x4 z = {0.f,0.f,0.f,0.f};
      ag[mi][ni] = z; au[mi][ni] = z;
    }

  for (int kt = 0; kt < K; kt += 64) {
    gload16(Ap + kt,          AsW);
    gload16(Ap + kt + r64K,   AsW + 4096);
    gload16(Gp + kt,          GsW);
    gload16(Gp + kt + r64K,   GsW + 4096);
    gload16(Up + kt,          UsW);
    gload16(Up + kt + r64K,   UsW + 4096);
    __syncthreads();
    #pragma unroll
    for (int kh = 0; kh < 2; kh++) {
      const int so = ((kh * 4 + lh) ^ fR) << 4;
      bf16x8 af[4], bg[2], bu[2];
      #pragma unroll
      for (int mi = 0; mi < 4; mi++)
        af[mi] = *(const bf16x8*)((const char*)As + (wm*64 + mi*16 + cl) * 128 + so);
      #pragma unroll
      for (int ni = 0; ni < 2; ni++) {
        bg[ni] = *(const bf16x8*)((const char*)Gs + (wn*32 + ni*16 + cl) * 128 + so);
        bu[ni] = *(const bf16x8*)((const char*)Us + (wn*32 + ni*16 + cl) * 128 + so);
      }
      #pragma unroll
      for (int mi = 0; mi < 4; mi++)
        #pragma unroll
        for (int ni = 0; ni < 2; ni++) {
          ag[mi][ni] = __builtin_amdgcn_mfma_f32_16x16x32_bf16(af[mi], bg[ni], ag[mi][ni], 0, 0, 0);
          au[mi][ni] = __builtin_amdgcn_mfma_f32_16x16x32_bf16(af[mi], bu[ni], au[mi][ni], 0, 0, 0);
        }
    }
    __syncthreads();
  }
  const int rbase = lh << 2;
  #pragma unroll
  for (int mi = 0; mi < 4; mi++) {
    #pragma unroll
    for (int ni = 0; ni < 2; ni++) {
      #pragma unroll
      for (int rr = 0; rr < 4; rr++) {
        int row = m0 + wm * 64 + mi * 16 + rbase + rr;
        int col = n0 + wn * 32 + ni * 16 + cl;
        float gv = ag[mi][ni][rr];
        float uv = au[mi][ni][rr];
        float val = gv / (1.0f + __expf(-gv)) * uv;
        act[(size_t)row * ldc + col] = f2b(val);
      }
    }
  }
}

// ============ 64x128 tile GEMM, BK=128, 4 waves, single-buffer 48KB ============
// 2D XCD chunking (4m x 2n) for square-ish GEMMs (Wo, Wd).
template<int MODE>
__global__ __launch_bounds__(256, 4)
void k_gemm6(const unsigned short* __restrict__ A, const unsigned short* __restrict__ B,
             float* __restrict__ Cf, unsigned short* __restrict__ Cb,
             const float* __restrict__ Res, const unsigned short* __restrict__ Gaux,
             int N, int K, int ldc) {
  __shared__ unsigned short As[8192];    // 64 x 128  (16KB)
  __shared__ unsigned short Bs[16384];   // 128 x 128 (32KB)
  const int t = threadIdx.x, l = t & 63, w = t >> 6;
  const int nbx = gridDim.x;
  const int nmt = gridDim.y;
  const int bid = blockIdx.y * nbx + blockIdx.x;
  const int xcd = bid & 7;
  const int local = bid >> 3;
  const int cm = nmt >> 2;
  const int cn = nbx >> 1;
  const int m0 = ((xcd & 3) * cm + (local % cm)) << 6;
  const int n0 = ((xcd >> 2) * cn + (local / cm)) << 7;
  const int srow = (w << 2) + (l >> 4);                // 0..15
  const int gcol = 8 * ((l & 15) ^ ((srow >> 1) & 7));
  const unsigned short* Ag = A + (size_t)(m0 + srow) * K + gcol;
  const unsigned short* Bg = B + (size_t)(n0 + srow) * K + gcol;
  const size_t r16K = (size_t)16 * K;
  unsigned short* AsW = As + (w << 9);
  unsigned short* BsW = Bs + (w << 9);
  const int cl = l & 15, lh = l >> 4;
  const int fR = (cl >> 1) & 7;
  f32x4 acc[4][2];
  #pragma unroll
  for (int mi = 0; mi < 4; mi++)
    #pragma unroll
    for (int ni = 0; ni < 2; ni++) { f32x4 z = {0.f,0.f,0.f,0.f}; acc[mi][ni] = z; }

  for (int kt = 0; kt < K; kt += 128) {
    gload16(Ag + kt,          AsW);
    gload16(Ag + kt +   r16K, AsW + 2048);
    gload16(Ag + kt + 2*r16K, AsW + 4096);
    gload16(Ag + kt + 3*r16K, AsW + 6144);
    gload16(Bg + kt,          BsW);
    gload16(Bg + kt +   r16K, BsW + 2048);
    gload16(Bg + kt + 2*r16K, BsW + 4096);
    gload16(Bg + kt + 3*r16K, BsW + 6144);
    gload16(Bg + kt + 4*r16K, BsW + 8192);
    gload16(Bg + kt + 5*r16K, BsW + 10240);
    gload16(Bg + kt + 6*r16K, BsW + 12288);
    gload16(Bg + kt + 7*r16K, BsW + 14336);
    __syncthreads();
    #pragma unroll
    for (int kk = 0; kk < 4; kk++) {
      const int so = ((kk * 4 + lh) ^ fR) << 4;
      bf16x8 af[4], bf[2];
      #pragma unroll
      for (int mi = 0; mi < 4; mi++)
        af[mi] = *(const bf16x8*)((const char*)As + (mi*16 + cl) * 256 + so);
      #pragma unroll
      for (int ni = 0; ni < 2; ni++)
        bf[ni] = *(const bf16x8*)((const char*)Bs + (w*32 + ni*16 + cl) * 256 + so);
      #pragma unroll
      for (int mi = 0; mi < 4; mi++)
        #pragma unroll
        for (int ni = 0; ni < 2; ni++)
          acc[mi][ni] = __builtin_amdgcn_mfma_f32_16x16x32_bf16(af[mi], bf[ni], acc[mi][ni], 0, 0, 0);
    }
    __syncthreads();
  }
  const int rbase = lh << 2;
  #pragma unroll
  for (int mi = 0; mi < 4; mi++) {
    #pragma unroll
    for (int ni = 0; ni < 2; ni++) {
      #pragma unroll
      for (int rr = 0; rr < 4; rr++) {
        int row = m0 + mi * 16 + rbase + rr;
        int col = n0 + w * 32 + ni * 16 + cl;
        size_t idx = (size_t)row * ldc + col;
        float val = acc[mi][ni][rr];
        if constexpr (MODE == 0) Cf[idx] = val;
        if constexpr (MODE == 1) Cf[idx] = val + Res[idx];
        if constexpr (MODE == 2) Cb[idx] = f2b(val);
        if constexpr (MODE == 3) {
          float gv = b2f(Gaux[idx]);
          val *= gv / (1.0f + __expf(-gv));
          Cb[idx] = f2b(val);
        }
      }
    }
  }
}

// ============ QKV GEMM + fused LoRA + fused RoPE -> dense bf16 qb/kb/vb =========
__global__ __launch_bounds__(256, 4)
void k_gemm7(const unsigned short* __restrict__ A, const unsigned short* __restrict__ B,
             unsigned short* __restrict__ qb, unsigned short* __restrict__ kb,
             unsigned short* __restrict__ vb,
             const float* __restrict__ ct, const float* __restrict__ st,
             int K,
             const float* __restrict__ ltq, const float* __restrict__ ltv,
             const float* __restrict__ lbq, const float* __restrict__ lbv) {
  __shared__ unsigned short As[4096];    // 64 x 64  (8KB)
  __shared__ unsigned short Bs[8192];    // 128 x 64 (16KB)
  const int t = threadIdx.x, l = t & 63, w = t >> 6;
  const int nbx = gridDim.x;                           // 48 n-tiles
  const int nmt = gridDim.y;                           // 32 m-tiles
  const int nwg = nbx * nmt;
  const int bid = blockIdx.y * nbx + blockIdx.x;
  const int sid = (bid & 7) * (nwg >> 3) + (bid >> 3);
  const int m0 = (sid % nmt) << 6;                     // m fast
  const int n0 = (sid / nmt) << 7;                     // n sliced per XCD
  const int srow = (w << 3) + (l >> 3);
  const int gcol = 8 * ((l & 7) ^ ((srow >> 1) & 7));
  const unsigned short* Ag = A + (size_t)(m0 + srow) * K + gcol;
  const unsigned short* Bg = B + (size_t)(n0 + srow) * K + gcol;
  const size_t r32K = (size_t)32 * K;
  unsigned short* AsW = As + (w << 9);
  unsigned short* BsW = Bs + (w << 9);
  const int cl = l & 15, lh = l >> 4;
  const int fR = (cl >> 1) & 7;
  f32x4 acc[4][2];
  #pragma unroll
  for (int mi = 0; mi < 4; mi++)
    #pragma unroll
    for (int ni = 0; ni < 2; ni++) { f32x4 z = {0.f,0.f,0.f,0.f}; acc[mi][ni] = z; }

  for (int kt = 0; kt < K; kt += 64) {
    gload16(Ag + kt,          AsW);
    gload16(Ag + kt +   r32K, AsW + 2048);
    gload16(Bg + kt,          BsW);
    gload16(Bg + kt +   r32K, BsW + 2048);
    gload16(Bg + kt + 2*r32K, BsW + 4096);
    gload16(Bg + kt + 3*r32K, BsW + 6144);
    __syncthreads();
    #pragma unroll
    for (int kh = 0; kh < 2; kh++) {
      const int so = ((kh * 4 + lh) ^ fR) << 4;
      bf16x8 af[4], bf[2];
      #pragma unroll
      for (int mi = 0; mi < 4; mi++)
        af[mi] = *(const bf16x8*)((const char*)As + (mi*16 + cl) * 128 + so);
      #pragma unroll
      for (int ni = 0; ni < 2; ni++)
        bf[ni] = *(const bf16x8*)((const char*)Bs + (w*16 + ni*64 + cl) * 128 + so);
      #pragma unroll
      for (int mi = 0; mi < 4; mi++)
        #pragma unroll
        for (int ni = 0; ni < 2; ni++)
          acc[mi][ni] = __builtin_amdgcn_mfma_f32_16x16x32_bf16(af[mi], bf[ni], acc[mi][ni], 0, 0, 0);
    }
    __syncthreads();
  }
  const int rbase = lh << 2;
  const int i0 = (w << 4) + cl;                // head-dim pair index 0..63
  const int col_lo = n0 + i0;
  const int reg = n0 >> 11;                    // 0=q, 1=k, 2=v
  const float* lt = nullptr;
  const float* lb_lo = nullptr;
  const float* lb_hi = nullptr;
  if (reg == 0)      { lt = ltq; lb_lo = lbq + (size_t)col_lo * RLORA;
                                 lb_hi = lbq + (size_t)(col_lo + 64) * RLORA; }
  else if (reg == 2) { lt = ltv; lb_lo = lbv + (size_t)(col_lo - 4096) * RLORA;
                                 lb_hi = lbv + (size_t)(col_lo - 4096 + 64) * RLORA; }
  float4 bl0={0,0,0,0}, bl1=bl0, bl2=bl0, bl3=bl0;
  float4 bh0=bl0, bh1=bl0, bh2=bl0, bh3=bl0;
  if (lt) {
    bl0 = ((const float4*)lb_lo)[0]; bl1 = ((const float4*)lb_lo)[1];
    bl2 = ((const float4*)lb_lo)[2]; bl3 = ((const float4*)lb_lo)[3];
    bh0 = ((const float4*)lb_hi)[0]; bh1 = ((const float4*)lb_hi)[1];
    bh2 = ((const float4*)lb_hi)[2]; bh3 = ((const float4*)lb_hi)[3];
  }
  unsigned short* outp = (reg == 0 ? qb : reg == 1 ? kb : vb);
  const int ocol = col_lo - reg * 2048;        // column within q/k/v tensor
  #pragma unroll
  for (int mi = 0; mi < 4; mi++) {
    #pragma unroll
    for (int rr = 0; rr < 4; rr++) {
      int row = m0 + mi * 16 + rbase + rr;
      float lo = acc[mi][0][rr];
      float hi = acc[mi][1][rr];
      if (lt) {
        const float4* tr = (const float4*)(lt + (size_t)row * RLORA);
        float4 t0 = tr[0], t1 = tr[1], t2 = tr[2], t3 = tr[3];
        lo += 2.0f * (t0.x*bl0.x + t0.y*bl0.y + t0.z*bl0.z + t0.w*bl0.w
                    + t1.x*bl1.x + t1.y*bl1.y + t1.z*bl1.z + t1.w*bl1.w
                    + t2.x*bl2.x + t2.y*bl2.y + t2.z*bl2.z + t2.w*bl2.w
                    + t3.x*bl3.x + t3.y*bl3.y + t3.z*bl3.z + t3.w*bl3.w);
        hi += 2.0f * (t0.x*bh0.x + t0.y*bh0.y + t0.z*bh0.z + t0.w*bh0.w
                    + t1.x*bh1.x + t1.y*bh1.y + t1.z*bh1.z + t1.w*bh1.w
                    + t2.x*bh2.x + t2.y*bh2.y + t2.z*bh2.z + t2.w*bh2.w
                    + t3.x*bh3.x + t3.y*bh3.y + t3.z*bh3.z + t3.w*bh3.w);
      }
      if (reg != 2) {                          // RoPE on q and k
        int s = row & (SEQLEN - 1);
        float c = ct[s * 64 + i0], sn = st[s * 64 + i0];
        float nlo = lo * c - hi * sn;
        float nhi = hi * c + lo * sn;
        lo = nlo; hi = nhi;
      }
      outp[(size_t)row * DMODEL + ocol]      = f2b(lo);
      outp[(size_t)row * DMODEL + ocol + 64] = f2b(hi);
    }
  }
}

// ---------------- NT GEMM fallback (B fp32, reg-staged, BK=32) ----------------
template<int MODE>
__global__ __launch_bounds__(256, 2)
void k_gemm(const unsigned short* __restrict__ A, const void* __restrict__ Bv,
            float* __restrict__ Cf, unsigned short* __restrict__ Cb,
            const float* __restrict__ Res, const unsigned short* __restrict__ Gaux,
            int N, int K, int ldc) {
  __shared__ unsigned char lds[128 * 32 * 2 * 2];
  unsigned char* As = lds;
  unsigned char* Bs = lds + 128 * 32 * 2;
  const int t = threadIdx.x;
  const int l = t & 63, w = t >> 6;
  const int wr = w >> 1, wc = w & 1;
  const int m0 = blockIdx.y << 7, n0 = blockIdx.x << 7;
  const int sr = t >> 1, skh = (t & 1) << 4;
  const int sByte = sr * 64 + (skh << 1);
  const int sSwz = (sr & 3) << 4;
  const unsigned short* Ap = A + (size_t)(m0 + sr) * K + skh;
  const float* Bp32 = (const float*)Bv + (size_t)(n0 + sr) * K + skh;
  const int kOff = (((l >> 4) << 4)) ^ ((l & 3) << 4);
  const int arow = wr * 64 + (l & 15);
  const int brow = wc * 64 + (l & 15);
  f32x4 acc[4][4];
  #pragma unroll
  for (int mi = 0; mi < 4; mi++)
    #pragma unroll
    for (int ni = 0; ni < 4; ni++) { f32x4 z = {0.f,0.f,0.f,0.f}; acc[mi][ni] = z; }

  for (int kt = 0; kt < K; kt += 32) {
    uint4 a0 = *(const uint4*)(Ap + kt);
    uint4 a1 = *(const uint4*)(Ap + kt + 8);
    *(uint4*)(As + ((sByte)      ^ sSwz)) = a0;
    *(uint4*)(As + ((sByte + 16) ^ sSwz)) = a1;
    float4 f0 = *(const float4*)(Bp32 + kt);
    float4 f1 = *(const float4*)(Bp32 + kt + 4);
    float4 f2 = *(const float4*)(Bp32 + kt + 8);
    float4 f3 = *(const float4*)(Bp32 + kt + 12);
    us8 q0, q1;
    q0[0]=f2b(f0.x); q0[1]=f2b(f0.y); q0[2]=f2b(f0.z); q0[3]=f2b(f0.w);
    q0[4]=f2b(f1.x); q0[5]=f2b(f1.y); q0[6]=f2b(f1.z); q0[7]=f2b(f1.w);
    q1[0]=f2b(f2.x); q1[1]=f2b(f2.y); q1[2]=f2b(f2.z); q1[3]=f2b(f2.w);
    q1[4]=f2b(f3.x); q1[5]=f2b(f3.y); q1[6]=f2b(f3.z); q1[7]=f2b(f3.w);
    *(us8*)(Bs + ((sByte)      ^ sSwz)) = q0;
    *(us8*)(Bs + ((sByte + 16) ^ sSwz)) = q1;
    __syncthreads();
    bf16x8 af[4], bfr[4];
    #pragma unroll
    for (int i = 0; i < 4; i++) {
      af[i]  = *(const bf16x8*)(As + (arow + 16 * i) * 64 + kOff);
      bfr[i] = *(const bf16x8*)(Bs + (brow + 16 * i) * 64 + kOff);
    }
    #pragma unroll
    for (int mi = 0; mi < 4; mi++)
      #pragma unroll
      for (int ni = 0; ni < 4; ni++)
        acc[mi][ni] = __builtin_amdgcn_mfma_f32_16x16x32_bf16(af[mi], bfr[ni], acc[mi][ni], 0, 0, 0);
    __syncthreads();
  }
  const int rbase = (l >> 4) << 2;
  const int cl = l & 15;
  #pragma unroll
  for (int mi = 0; mi < 4; mi++) {
    #pragma unroll
    for (int ni = 0; ni < 4; ni++) {
      #pragma unroll
      for (int rr = 0; rr < 4; rr++) {
        int row = m0 + wr * 64 + mi * 16 + rbase + rr;
        int col = n0 + wc * 64 + ni * 16 + cl;
        size_t idx = (size_t)row * ldc + col;
        float val = acc[mi][ni][rr];
        if constexpr (MODE == 0) Cf[idx] = val;
        if constexpr (MODE == 1) Cf[idx] = val + Res[idx];
        if constexpr (MODE == 2) Cb[idx] = f2b(val);
        if constexpr (MODE == 3) {
          float gv = b2f(Gaux[idx]);
          val *= gv / (1.0f + __expf(-gv));
          Cb[idx] = f2b(val);
        }
      }
    }
  }
}

// ---------------- merged LoRA down: tbq/tbv = h Aq^T / h Av^T ----------------
__global__ void k_lora_down2(const unsigned short* __restrict__ h,
                             const float* __restrict__ Aq, const float* __restrict__ Av,
                             float* __restrict__ tbq, float* __restrict__ tbv) {
  int t = threadIdx.x;
  int m = blockIdx.x * 8 + (t >> 5), r = t & 31;
  const float* ar = (r < 16) ? (Aq + (size_t)r * DMODEL)
                             : (Av + (size_t)(r - 16) * DMODEL);
  const unsigned short* hr = h + (size_t)m * DMODEL;
  float acc = 0.f;
  for (int d = 0; d < DMODEL; d += 4) {
    ushort4 hv = *(const ushort4*)(hr + d);
    float4 av = *(const float4*)(ar + d);
    acc += b2f(hv.x)*av.x + b2f(hv.y)*av.y + b2f(hv.z)*av.z + b2f(hv.w)*av.w;
  }
  if (r < 16) tbq[(size_t)m * RLORA + r] = acc;
  else        tbv[(size_t)m * RLORA + (r - 16)] = acc;
}

// fallback lora kernels (fp32 path only)
__global__ void k_lora_down(const unsigned short* __restrict__ h, const float* __restrict__ Am,
                            float* __restrict__ tb) {
  int t = threadIdx.x;
  int m = blockIdx.x * 16 + (t >> 4), r = t & 15;
  const unsigned short* hr = h + (size_t)m * DMODEL;
  const float* ar = Am + (size_t)r * DMODEL;
  float acc = 0.f;
  for (int d = 0; d < DMODEL; d += 4) {
    ushort4 hv = *(const ushort4*)(hr + d);
    float4 av = *(const float4*)(ar + d);
    acc += b2f(hv.x)*av.x + b2f(hv.y)*av.y + b2f(hv.z)*av.z + b2f(hv.w)*av.w;
  }
  tb[(size_t)m * RLORA + r] = acc;
}

__global__ void k_lora_up(const float* __restrict__ tb, const float* __restrict__ Bm,
                          float* __restrict__ out, int ldc) {
  int tid = blockIdx.x * 256 + threadIdx.x;
  int m = tid >> 11, e = tid & (DMODEL - 1);
  const float* tr = tb + (size_t)m * RLORA;
  const float* br = Bm + (size_t)e * RLORA;
  float acc = 0.f;
  #pragma unroll
  for (int r = 0; r < RLORA; r += 4) {
    float4 tv = *(const float4*)(tr + r);
    float4 bv = *(const float4*)(br + r);
    acc += tv.x*bv.x + tv.y*bv.y + tv.z*bv.z + tv.w*bv.w;
  }
  out[(size_t)m * ldc + e] += 2.0f * acc;
}

// ---------------- RoPE tables ----------------
__global__ void k_rope_table(float* __restrict__ ct, float* __restrict__ st) {
  int tid = blockIdx.x * 256 + threadIdx.x;
  int s = tid >> 6, i = tid & 63;
  float inv = __expf(-((float)i / 64.0f) * logf(10000.0f));
  float ang = (float)s * inv;
  ct[tid] = cosf(ang);
  st[tid] = sinf(ang);
}

// fallback rope (f32 qkv -> qb, kb, vb dense)
__global__ void k_rope2(const float* __restrict__ qkv,
                        const float* __restrict__ ct, const float* __restrict__ st,
                        unsigned short* __restrict__ qb, unsigned short* __restrict__ kb,
                        unsigned short* __restrict__ vb) {
  int tid = blockIdx.x * 256 + threadIdx.x;
  int i = tid & 63;
  int hh = (tid >> 6) & (NHEAD - 1);
  int s = (tid >> 10) & (SEQLEN - 1);
  int b = tid >> 20;
  size_t ibase = ((size_t)(b * SEQLEN + s)) * QKVS + hh * HEADD;
  size_t obase = ((size_t)(b * SEQLEN + s)) * DMODEL + hh * HEADD;
  float c = ct[s * 64 + i], sn = st[s * 64 + i];
  float q0 = qkv[ibase + i], q1 = qkv[ibase + i + 64];
  qb[obase + i]      = f2b(q0 * c - q1 * sn);
  qb[obase + i + 64] = f2b(q1 * c + q0 * sn);
  float k0 = qkv[ibase + 2048 + i], k1 = qkv[ibase + 2048 + i + 64];
  kb[obase + i]      = f2b(k0 * c - k1 * sn);
  kb[obase + i + 64] = f2b(k1 * c + k0 * sn);
  vb[obase + i]      = f2b(qkv[ibase + 4096 + i]);
  vb[obase + i + 64] = f2b(qkv[ibase + 4096 + i + 64]);
}

// ---------------- fused causal attention, MFMA bf16 inputs ----------------
// T14 async-STAGE: K/V tile kb+1 prefetched into registers AFTER barrier B.
__global__ __launch_bounds__(256, 2)
void k_attn_bf16(const unsigned short* __restrict__ qbp, const unsigned short* __restrict__ kbp,
                 const unsigned short* __restrict__ vbp, const int* __restrict__ am,
                 unsigned short* __restrict__ o, int vstride) {
  __shared__ unsigned char Kls[64 * 256];
  __shared__ unsigned char Vls[128 * 128];
  __shared__ unsigned char Pls[64 * 128];
  const int qt = blockIdx.x, hh = blockIdx.y, b = blockIdx.z;
  const int t = threadIdx.x, l = t & 63, w = t >> 6;
  const int cl = l & 15, lh = l >> 4;
  const int rbase = lh << 2;
  const int prow = t >> 4;
  const int pc   = t & 15;

  #pragma unroll
  for (int ii = 0; ii < 4; ii++) {
    int row = prow + 16 * ii;
    uint4 u = *(const uint4*)(qbp + ((size_t)(b*SEQLEN + qt*64 + row)) * DMODEL + hh * HEADD + pc * 8);
    *(uint4*)(Kls + ((row * 256 + pc * 16) ^ ((row & 7) << 4))) = u;
  }
  uint4 kreg[4], vreg[4];
  #pragma unroll
  for (int ii = 0; ii < 4; ii++) {
    int row = prow + 16 * ii;
    kreg[ii] = *(const uint4*)(kbp + ((size_t)(b*SEQLEN + row)) * DMODEL + hh * HEADD + pc * 8);
    vreg[ii] = *(const uint4*)(vbp + ((size_t)(b*SEQLEN + row)) * vstride + hh * HEADD + pc * 8);
  }
  __syncthreads();
  bf16x8 qf[4];
  {
    int row = w * 16 + cl;
    int swz = (row & 7) << 4;
    #pragma unroll
    for (int kt = 0; kt < 4; kt++)
      qf[kt] = *(const bf16x8*)(Kls + ((row * 256 + kt * 64 + lh * 16) ^ swz));
  }

  f32x4 oacc[8];
  #pragma unroll
  for (int i = 0; i < 8; i++) { f32x4 z = {0.f,0.f,0.f,0.f}; oacc[i] = z; }
  float mrun[4], lrun[4];
  #pragma unroll
  for (int r = 0; r < 4; r++) { mrun[r] = -3e38f; lrun[r] = 0.f; }

  for (int kb = 0; kb <= qt; kb++) {
    __syncthreads();
    #pragma unroll
    for (int ii = 0; ii < 4; ii++) {
      int row = prow + 16 * ii;
      *(uint4*)(Kls + ((row * 256 + pc * 16) ^ ((row & 7) << 4))) = kreg[ii];
    }
    #pragma unroll
    for (int ii = 0; ii < 4; ii++) {
      int n = prow + 16 * ii;
      uint4 a = vreg[ii];
      uint4 p;
      p.x = __shfl_xor(a.x, 16); p.y = __shfl_xor(a.y, 16);
      p.z = __shfl_xor(a.z, 16); p.w = __shfl_xor(a.w, 16);
      if (!(l & 16)) {
        int d0 = pc * 8, nb = n * 2;
        unsigned int wd[8];
        wd[0] = (a.x & 0xffffu) | (p.x << 16);
        wd[1] = (a.x >> 16)     | (p.x & 0xffff0000u);
        wd[2] = (a.y & 0xffffu) | (p.y << 16);
        wd[3] = (a.y >> 16)     | (p.y & 0xffff0000u);
        wd[4] = (a.z & 0xffffu) | (p.z << 16);
        wd[5] = (a.z >> 16)     | (p.z & 0xffff0000u);
        wd[6] = (a.w & 0xffffu) | (p.w << 16);
        wd[7] = (a.w >> 16)     | (p.w & 0xffff0000u);
        #pragma unroll
        for (int e = 0; e < 8; e++)
          *(unsigned int*)(Vls + (((d0 + e) * 128 + nb) ^ vswz(d0 + e))) = wd[e];
      }
    }
    __syncthreads();
    if (kb < qt) {
      #pragma unroll
      for (int ii = 0; ii < 4; ii++) {
        int row = prow + 16 * ii;
        kreg[ii] = *(const uint4*)(kbp + ((size_t)(b*SEQLEN + (kb+1)*64 + row)) * DMODEL + hh * HEADD + pc * 8);
        vreg[ii] = *(const uint4*)(vbp + ((size_t)(b*SEQLEN + (kb+1)*64 + row)) * vstride + hh * HEADD + pc * 8);
      }
    }
    f32x4 sacc[4];
    #pragma unroll
    for (int nt = 0; nt < 4; nt++) { f32x4 z = {0.f,0.f,0.f,0.f}; sacc[nt] = z; }
    #pragma unroll
    for (int kt = 0; kt < 4; kt++) {
      #pragma unroll
      for (int nt = 0; nt < 4; nt++) {
        int row = nt * 16 + cl;
        bf16x8 kf = *(const bf16x8*)(Kls + ((row * 256 + kt * 64 + lh * 16) ^ ((row & 7) << 4)));
        sacc[nt] = __builtin_amdgcn_mfma_f32_16x16x32_bf16(qf[kt], kf, sacc[nt], 0, 0, 0);
      }
    }
    float p[4][4];
    float mt[4] = {-3e38f, -3e38f, -3e38f, -3e38f};
    #pragma unroll
    for (int nt = 0; nt < 4; nt++) {
      int kg = kb * 64 + nt * 16 + cl;
      float pad = (1.0f - (float)am[b * SEQLEN + kg]) * (-1e9f);
      #pragma unroll
      for (int r = 0; r < 4; r++) {
        int qg = qt * 64 + w * 16 + rbase + r;
        float s = sacc[nt][r] * 0.08838834764831845f + pad;
        if (kg > qg) s = -1e30f;
        p[nt][r] = s;
        mt[r] = fmaxf(mt[r], s);
      }
    }
    #pragma unroll
    for (int r = 0; r < 4; r++) {
      float m = mt[r];
      m = fmaxf(m, __shfl_xor(m, 1)); m = fmaxf(m, __shfl_xor(m, 2));
      m = fmaxf(m, __shfl_xor(m, 4)); m = fmaxf(m, __shfl_xor(m, 8));
      mt[r] = m;
    }
    float corr[4];
    #pragma unroll
    for (int r = 0; r < 4; r++) {
      float mnew = fmaxf(mrun[r], mt[r]);
      corr[r] = __expf(mrun[r] - mnew);
      mrun[r] = mnew;
    }
    float ps[4] = {0.f, 0.f, 0.f, 0.f};
    #pragma unroll
    for (int nt = 0; nt < 4; nt++)
      #pragma unroll
      for (int r = 0; r < 4; r++) {
        p[nt][r] = __expf(p[nt][r] - mrun[r]);
        ps[r] += p[nt][r];
      }
    #pragma unroll
    for (int r = 0; r < 4; r++) {
      float s = ps[r];
      s += __shfl_xor(s, 1); s += __shfl_xor(s, 2);
      s += __shfl_xor(s, 4); s += __shfl_xor(s, 8);
      lrun[r] = lrun[r] * corr[r] + s;
    }
    #pragma unroll
    for (int nt = 0; nt < 4; nt++)
      #pragma unroll
      for (int r = 0; r < 4; r++) {
        int row = w * 16 + rbase + r;
        *(unsigned short*)(Pls + ((row * 128 + (nt * 16 + cl) * 2) ^ ((row & 7) << 4))) = f2b(p[nt][r]);
      }
    #pragma unroll
    for (int dt = 0; dt < 8; dt++)
      #pragma unroll
      for (int r = 0; r < 4; r++) oacc[dt][r] *= corr[r];
    {
      int prw = w * 16 + cl, pswz = (prw & 7) << 4;
      bf16x8 pf0 = *(const bf16x8*)(Pls + ((prw * 128 +  0 + lh * 16) ^ pswz));
      bf16x8 pf1 = *(const bf16x8*)(Pls + ((prw * 128 + 64 + lh * 16) ^ pswz));
      #pragma unroll
      for (int dt = 0; dt < 8; dt++) {
        int drow = dt * 16 + cl;
        bf16x8 vf0 = *(const bf16x8*)(Vls + ((drow * 128 +  0 + lh * 16) ^ vswz(drow)));
        bf16x8 vf1 = *(const bf16x8*)(Vls + ((drow * 128 + 64 + lh * 16) ^ vswz(drow)));
        oacc[dt] = __builtin_amdgcn_mfma_f32_16x16x32_bf16(pf0, vf0, oacc[dt], 0, 0, 0);
        oacc[dt] = __builtin_amdgcn_mfma_f32_16x16x32_bf16(pf1, vf1, oacc[dt], 0, 0, 0);
      }
    }
  }
  size_t obase = (((size_t)b * SEQLEN + qt * 64 + w * 16) * NHEAD + hh) * HEADD;
  #pragma unroll
  for (int r = 0; r < 4; r++) {
    float inv = 1.0f / lrun[r];
    int row = rbase + r;
    #pragma unroll
    for (int dt = 0; dt < 8; dt++)
      o[obase + (size_t)row * (NHEAD * HEADD) + dt * 16 + cl] = f2b(oacc[dt][r] * inv);
  }
}

// ---------------- pooling + final RMS ----------------
__global__ void k_pool(const float* __restrict__ x, const int* __restrict__ am,
                       const float* __restrict__ fn, float* __restrict__ pooled) {
  int b = blockIdx.x, t = threadIdx.x;
  __shared__ float red[4];
  float fc = 0.f;
  for (int i = t; i < SEQLEN; i += 256) fc += (float)am[b * SEQLEN + i];
  for (int m = 32; m; m >>= 1) fc += __shfl_xor(fc, m);
  if ((t & 63) == 0) red[t >> 6] = fc;
  __syncthreads();
  int idx = (int)(red[0] + red[1] + red[2] + red[3]) - 1;
  const float* xr = x + ((size_t)b * SEQLEN + idx) * DMODEL;
  float4 a = ((const float4*)xr)[t], c = ((const float4*)xr)[t + 256];
  float ss = a.x*a.x + a.y*a.y + a.z*a.z + a.w*a.w
           + c.x*c.x + c.y*c.y + c.z*c.z + c.w*c.w;
  for (int m = 32; m; m >>= 1) ss += __shfl_xor(ss, m);
  __syncthreads();
  if ((t & 63) == 0) red[t >> 6] = ss;
  __syncthreads();
  ss = red[0] + red[1] + red[2] + red[3];
  float rs = rsqrtf(ss * (1.0f / DMODEL) + 1e-5f);
  float4 w0 = ((const float4*)fn)[t], w1 = ((const float4*)fn)[t + 256];
  float4 o0, o1;
  o0.x = a.x*rs*w0.x; o0.y = a.y*rs*w0.y; o0.z = a.z*rs*w0.z; o0.w = a.w*rs*w0.w;
  o1.x = c.x*rs*w1.x; o1.y = c.y*rs*w1.y; o1.z = c.z*rs*w1.z; o1.w = c.w*rs*w1.w;
  ((float4*)(pooled + (size_t)b * DMODEL))[t] = o0;
  ((float4*)(pooled + (size_t)b * DMODEL))[t + 256] = o1;
}

// ---------------- classification head ----------------
__global__ void k_head1(const float* __restrict__ pooled, const float* __restrict__ W1,
                        const float* __restrict__ b1, float* __restrict__ h1) {
  int bi = blockIdx.x;
  int b = bi >> 3, e = ((bi & 7) << 8) + threadIdx.x;
  const float* pr = pooled + (size_t)b * DMODEL;
  const float* wr = W1 + (size_t)e * DMODEL;
  float acc = 0.f;
  for (int d = 0; d < DMODEL; d += 4) {
    float4 pv = *(const float4*)(pr + d);
    float4 wv = *(const float4*)(wr + d);
    acc += pv.x*wv.x + pv.y*wv.y + pv.z*wv.z + pv.w*wv.w;
  }
  h1[(size_t)b * DMODEL + e] = tanhf(acc + b1[e]);
}

__global__ void k_head2(const float* __restrict__ h1, const float* __restrict__ W2,
                        const float* __restrict__ b2, float* __restrict__ out) {
  int bi = blockIdx.x;
  int b = bi / 3, c = bi % 3;
  int l = threadIdx.x;
  float acc = 0.f;
  for (int e = l; e < DMODEL; e += 64)
    acc += h1[(size_t)b * DMODEL + e] * W2[(size_t)c * DMODEL + e];
  for (int m = 32; m; m >>= 1) acc += __shfl_xor(acc, m);
  if (l == 0) out[b * 3 + c] = acc + b2[c];
}

__global__ void k_sentinel(float* out) {
  if (threadIdx.x < 6) out[threadIdx.x] = -12345.0f;
}

// ---------------- launch ----------------
extern "C" void kernel_launch(void* const* d_in, const int* in_sizes, int n_in,
                              void* d_out, int out_size, void* d_ws, size_t ws_size,
                              hipStream_t stream) {
  const int*   ids = (const int*)d_in[0];
  const int*   am  = (const int*)d_in[1];
  const float* emb = (const float*)d_in[2];
  const float* Wq  = (const float*)d_in[3];
  const float* Wk  = (const float*)d_in[4];
  const float* Wv  = (const float*)d_in[5];
  const float* Wo  = (const float*)d_in[6];
  const float* Aq  = (const float*)d_in[7];
  const float* Bq  = (const float*)d_in[8];
  const float* Av  = (const float*)d_in[9];
  const float* Bv  = (const float*)d_in[10];
  const float* Wg  = (const float*)d_in[11];
  const float* Wu  = (const float*)d_in[12];
  const float* Wd  = (const float*)d_in[13];
  const float* n1  = (const float*)d_in[14];
  const float* n2  = (const float*)d_in[15];
  const float* fn  = (const float*)d_in[16];
  const float* hW1 = (const float*)d_in[17];
  const float* hb1 = (const float*)d_in[18];
  const float* hW2 = (const float*)d_in[19];
  const float* hb2 = (const float*)d_in[20];
  float* out = (float*)d_out;

  // workspace layout
  const size_t XOFF    = 0;                       // x f32 16MB
  const size_t HOFF    = 16777216;                // h bf16 8MB
  const size_t QBOFF   = 25165824;                // qb bf16 8MB
  const size_t KBOFF   = 33554432;                // kb bf16 8MB
  const size_t VBOFF   = 41943040;                // vb bf16 8MB
  const size_t OOFF    = 50331648;                // o bf16 8MB
  const size_t GOFF    = 58720256;                // g bf16 32MB (fallback only)
  const size_t ACTOFF  = 92274688;                // act bf16 32MB
  const size_t QKV32OFF= 125829120;               // qkv f32 48MB (fallback only)
  const size_t TOFF    = 176160768;               // tails
  const size_t NEED = TOFF + 131072 + 131072 + 262144 + 262144 + 16384 + 16384;
  if (ws_size < NEED) {
    k_sentinel<<<1, 64, 0, stream>>>(out);
    return;
  }
  const size_t W16OFF   = (NEED + 255) & ~(size_t)255;
  const size_t W16BYTES = 536870912ull;
  const bool   use16    = ws_size >= W16OFF + W16BYTES;

  char* ws = (char*)d_ws;
  float*          x     = (float*)(ws + XOFF);
  unsigned short* h     = (unsigned short*)(ws + HOFF);
  unsigned short* qb    = (unsigned short*)(ws + QBOFF);
  unsigned short* kb    = (unsigned short*)(ws + KBOFF);
  unsigned short* vb    = (unsigned short*)(ws + VBOFF);
  unsigned short* o     = (unsigned short*)(ws + OOFF);
  unsigned short* g     = (unsigned short*)(ws + GOFF);
  unsigned short* act   = (unsigned short*)(ws + ACTOFF);
  float*          qkv32 = (float*)(ws + QKV32OFF);
  float* tbq    = (float*)(ws + TOFF);
  float* tbv    = (float*)(ws + TOFF + 131072);
  float* ct     = (float*)(ws + TOFF + 262144);
  float* st     = (float*)(ws + TOFF + 262144 + 262144);
  float* pooled = (float*)(ws + TOFF + 262144 + 524288);
  float* h1     = (float*)(ws + TOFF + 262144 + 524288 + 16384);

  unsigned short* w16 = (unsigned short*)(ws + W16OFF);
  const size_t DD = (size_t)DMODEL * DMODEL;      // 4M elems
  const size_t FD = (size_t)FFDIM * DMODEL;       // 16M elems
  unsigned short* wqkv16 = w16;                              // L*3*DD
  unsigned short* wo16   = w16 + 4ull * 3 * DD;              // L*DD
  unsigned short* wg16   = wo16 + 4ull * DD;                 // L*FD
  unsigned short* wu16   = wg16 + 4ull * FD;
  unsigned short* wd16   = wu16 + 4ull * FD;
  if (use16) {
    k_cvtqkv<<<2048, 256, 0, stream>>>(Wq, Wk, Wv, wqkv16);
    k_cvt16<<<2048, 256, 0, stream>>>(Wo, wo16, (int)(4 * DD / 8));
    k_cvt16<<<2048, 256, 0, stream>>>(Wg, wg16, (int)(4 * FD / 8));
    k_cvt16<<<2048, 256, 0, stream>>>(Wu, wu16, (int)(4 * FD / 8));
    k_cvt16<<<2048, 256, 0, stream>>>(Wd, wd16, (int)(4 * FD / 8));
  }

  k_embed<<<NTOK, 256, 0, stream>>>(ids, emb, x);
  k_rope_table<<<SEQLEN * 64 / 256, 256, 0, stream>>>(ct, st);

  dim3 g16(16, 16), gqkv(48, 32), gffn(64, 16), gsq(16, 32), ga(SEQLEN / 64, NHEAD, NBATCH);
  for (int lay = 0; lay < NLAYER; lay++) {
    const float* Bq_l = Bq + (size_t)lay * DMODEL * RLORA;
    const float* Bv_l = Bv + (size_t)lay * DMODEL * RLORA;
    k_rmsnorm<<<NTOK, 256, 0, stream>>>(x, n1 + (size_t)lay * DMODEL, h);
    if (use16) {
      k_lora_down2<<<NTOK / 8, 256, 0, stream>>>(h, Aq + (size_t)lay * RLORA * DMODEL,
                                                 Av + (size_t)lay * RLORA * DMODEL, tbq, tbv);
      // QKV GEMM + fused LoRA + fused RoPE -> qb/kb/vb bf16 directly
      k_gemm7<<<gqkv, 256, 0, stream>>>(h, wqkv16 + lay*3*DD, qb, kb, vb, ct, st,
                                        DMODEL, tbq, tbv, Bq_l, Bv_l);
      k_attn_bf16<<<ga, 256, 0, stream>>>(qb, kb, vb, am, o, DMODEL);
      // Wo: 64x128 tile BK=128, 2D XCD chunking
      k_gemm6<1><<<gsq, 256, 0, stream>>>(o, wo16 + lay*DD, x, nullptr, x, nullptr, DMODEL, DMODEL, DMODEL);
      k_rmsnorm<<<NTOK, 256, 0, stream>>>(x, n2 + (size_t)lay * DMODEL, h);
      // FFN gate+up fused, m-fast order
      k_ffn<<<gffn, 512, 0, stream>>>(h, wg16 + lay*FD, wu16 + lay*FD, act, FFDIM, DMODEL, FFDIM);
      // Wd: 64x128 tile BK=128, K=8192
      k_gemm6<1><<<gsq, 256, 0, stream>>>(act, wd16 + lay*FD, x, nullptr, x, nullptr, DMODEL, FFDIM, DMODEL);
    } else {
      k_lora_down<<<NTOK / 16, 256, 0, stream>>>(h, Aq + (size_t)lay * RLORA * DMODEL, tbq);
      k_lora_down<<<NTOK / 16, 256, 0, stream>>>(h, Av + (size_t)lay * RLORA * DMODEL, tbv);
      k_gemm<0><<<g16, 256, 0, stream>>>(h, Wq + lay*DD, qkv32,        nullptr, nullptr, nullptr, DMODEL, DMODEL, QKVS);
      k_gemm<0><<<g16, 256, 0, stream>>>(h, Wk + lay*DD, qkv32 + 2048, nullptr, nullptr, nullptr, DMODEL, DMODEL, QKVS);
      k_gemm<0><<<g16, 256, 0, stream>>>(h, Wv + lay*DD, qkv32 + 4096, nullptr, nullptr, nullptr, DMODEL, DMODEL, QKVS);
      k_lora_up<<<NTOK * DMODEL / 256, 256, 0, stream>>>(tbq, Bq_l, qkv32, QKVS);
      k_lora_up<<<NTOK * DMODEL / 256, 256, 0, stream>>>(tbv, Bv_l, qkv32 + 4096, QKVS);
      k_rope2<<<NBATCH * SEQLEN * NHEAD * 64 / 256, 256, 0, stream>>>(qkv32, ct, st, qb, kb, vb);
      k_attn_bf16<<<ga, 256, 0, stream>>>(qb, kb, vb, am, o, DMODEL);
      k_gemm<1><<<g16, 256, 0, stream>>>(o, Wo + lay*DD, x, nullptr, x, nullptr, DMODEL, DMODEL, DMODEL);
      k_rmsnorm<<<NTOK, 256, 0, stream>>>(x, n2 + (size_t)lay * DMODEL, h);
      k_gemm<2><<<dim3(64,16), 256, 0, stream>>>(h, Wg + lay*FD, nullptr, g, nullptr, nullptr, FFDIM, DMODEL, FFDIM);
      k_gemm<3><<<dim3(64,16), 256, 0, stream>>>(h, Wu + lay*FD, nullptr, act, nullptr, g, FFDIM, DMODEL, FFDIM);
      k_gemm<1><<<g16, 256, 0, stream>>>(act, Wd + lay*FD, x, nullptr, x, nullptr, DMODEL, FFDIM, DMODEL);
    }
  }
  k_pool<<<NBATCH, 256, 0, stream>>>(x, am, fn, pooled);
  k_head1<<<16, 256, 0, stream>>>(pooled, hW1, hb1, h1);
  k_head2<<<6, 64, 0, stream>>>(h1, hW2, hb2, out);
}